// Round 19
// baseline (3880.716 us; speedup 1.0000x reference)
//
#include <hip/hip_runtime.h>
#include <math.h>

#define BB 16
#define TT 16
#define EE 128
#define KS 15
#define MM 41
#define OO 4
#define VR 7
#define SS 27
#define NSTEP 15
#define PP (MM*MM)
#define NROWS (BB*PP)

#define RAWS_OFF 0
#define SPS_OFF  1613760
#define MAPS_OFF 3227520

#define PM 55
#define PMSZ (PM*PM)
#define NPS 3
#define WS 34              // wsm16 row stride (u16): word-stride 17, conflict-free

typedef __attribute__((ext_vector_type(8))) short short8v;
typedef __attribute__((ext_vector_type(4))) float f32x4;
typedef __attribute__((ext_vector_type(2))) __bf16 bf16x2;
typedef unsigned short ushort;
typedef unsigned int uint;

__device__ __forceinline__ float sigf(float x) { return 1.f / (1.f + expf(-x)); }

__device__ __forceinline__ ushort f2bf(float x) {
    unsigned int u = __float_as_uint(x);
    u += 0x7FFF + ((u >> 16) & 1);
    return (ushort)(u >> 16);
}
__device__ __forceinline__ float bf2f(ushort u) {
    return __uint_as_float((unsigned int)u << 16);
}

__device__ __forceinline__ int rotoff(int o, int r, int c) {
    int ir, ic;
    if (o == 0)      { ir = r;      ic = c;      }
    else if (o == 1) { ir = c;      ic = 14 - r; }
    else if (o == 2) { ir = 14 - r; ic = 14 - c; }
    else             { ir = 14 - c; ic = r;      }
    return ir * 15 + ic;
}

// pose is bf16 end-to-end now (softmax probs in [0,1]; reg16 output was
// already bf16-rounded, so no accuracy change beyond the comparison floor).
__global__ void k_init(ushort* __restrict__ pose16) {
    int idx = blockIdx.x * 256 + threadIdx.x;
    if (idx < BB * OO * MM * MM) {
        int r = idx % (OO * MM * MM);
        pose16[idx] = (r == (20 * MM + 20)) ? (ushort)0x3F80 : (ushort)0;
    }
}

// Wt[jp][k] bf16 (B^T layout for MFMA), jp = jj*4+g; bc[jp] = bih+bhh
__global__ void k_prep(const float* __restrict__ wih, const float* __restrict__ whh,
                       const float* __restrict__ bih, const float* __restrict__ bhh,
                       ushort* __restrict__ Wt, float* __restrict__ bc) {
    int idx = blockIdx.x * 256 + threadIdx.x;   // [0, 512*256)
    int jp = idx >> 8, k = idx & 255;
    int jj = jp >> 2, g = jp & 3, j = g * 128 + jj;
    float v = (k < 128) ? wih[j * 128 + k] : whh[j * 128 + (k - 128)];
    Wt[(size_t)jp * 256 + k] = f2bf(v);
    if (idx < 512) {
        int jj2 = idx >> 2, g2 = idx & 3, j2 = g2 * 128 + jj2;
        bc[idx] = bih[j2] + bhh[j2];
    }
}

// register v2: bf16 LDS. ps16 24.2 KB + wsm16 15.3 KB = 39.5 KB -> 4 blocks/CU
// (was 80.9 KB -> 1 block/CU, occupancy 3.9%). wsm16 staged with coalesced
// global reads + word-stride-17 writes (conflict-free; old fp32 layout was
// 8-way, 9.5M conflict cycles). Hot-loop weight reads are wave-uniform
// broadcasts (ec uniform per wave): 4 aligned uint loads + 8 unpack shifts.
// Index math identical to R4-verified version.
__global__ __launch_bounds__(256) void k_register(const float* __restrict__ images,
                                                  const ushort* __restrict__ pose16,
                                                  ushort* __restrict__ reg16, int t) {
    __shared__ ushort ps16[OO * PMSZ];   // 24,200 B
    __shared__ ushort wsm16[225 * WS];   // 15,300 B
    const int p0 = blockIdx.x * 256;
    const int eq = blockIdx.y;
    const int b  = blockIdx.z;
    const int tid = threadIdx.x;

    for (int i = tid; i < OO * PMSZ; i += 256) {
        int o = i / PMSZ, rem = i % PMSZ, r = rem / PM, c = rem % PM;
        ushort v = 0;
        if (r >= VR && r < VR + MM && c >= VR && c < VR + MM)
            v = pose16[(((size_t)b * OO + o) * MM + (r - VR)) * MM + (c - VR)];
        ps16[i] = v;
    }
    const float* img = images + ((size_t)(b * TT + t) * EE + eq * 32) * 225;
    for (int i = tid; i < 32 * 225; i += 256) {
        int e = i / 225, k = i - e * 225;     // consecutive tid -> consecutive k (coalesced)
        wsm16[k * WS + e] = f2bf(img[e * 225 + k]);
    }
    __syncthreads();

    const int px = tid & 63;
    const int ec = tid >> 6;                  // wave-uniform
    int pbase[4];
    #pragma unroll
    for (int i = 0; i < 4; ++i) {
        int p = p0 + px + 64 * i;
        int pc = (p < PP) ? p : 0;
        int y = pc / MM, x = pc - y * MM;
        pbase[i] = (y + 2 * VR) * PM + (x + 2 * VR);
    }

    float acc[4][8];
    #pragma unroll
    for (int i = 0; i < 4; ++i)
        #pragma unroll
        for (int j = 0; j < 8; ++j) acc[i][j] = 0.f;

    for (int R = 0; R < 15; ++R) {
        #pragma unroll 5
        for (int C = 0; C < 15; ++C) {
            const ushort* wrow = &wsm16[(R * 15 + C) * WS + ec * 8];
            uint w01 = *(const uint*)(wrow);      // 4B-aligned: 68*tap + 16*ec
            uint w23 = *(const uint*)(wrow + 2);
            uint w45 = *(const uint*)(wrow + 4);
            uint w67 = *(const uint*)(wrow + 6);
            float w[8];
            w[0] = bf2f((ushort)(w01 & 0xffffu)); w[1] = bf2f((ushort)(w01 >> 16));
            w[2] = bf2f((ushort)(w23 & 0xffffu)); w[3] = bf2f((ushort)(w23 >> 16));
            w[4] = bf2f((ushort)(w45 & 0xffffu)); w[5] = bf2f((ushort)(w45 >> 16));
            w[6] = bf2f((ushort)(w67 & 0xffffu)); w[7] = bf2f((ushort)(w67 >> 16));
            #pragma unroll
            for (int i = 0; i < 4; ++i) {
                float a0 = bf2f(ps16[0 * PMSZ + pbase[i] - R * PM - C]);
                float a1 = bf2f(ps16[1 * PMSZ + pbase[i] + (C - 14) * PM - R]);
                float a2 = bf2f(ps16[2 * PMSZ + pbase[i] + (R - 14) * PM + (C - 14)]);
                float a3 = bf2f(ps16[3 * PMSZ + pbase[i] - C * PM + (R - 14)]);
                float s = (a0 + a1) + (a2 + a3);
                acc[i][0] += s * w[0]; acc[i][1] += s * w[1];
                acc[i][2] += s * w[2]; acc[i][3] += s * w[3];
                acc[i][4] += s * w[4]; acc[i][5] += s * w[5];
                acc[i][6] += s * w[6]; acc[i][7] += s * w[7];
            }
        }
    }

    #pragma unroll
    for (int i = 0; i < 4; ++i) {
        int p = p0 + px + 64 * i;
        if (p < PP) {
            ushort* dst = reg16 + ((size_t)b * PP + p) * EE + eq * 32 + ec * 8;
            ushort u[8];
            #pragma unroll
            for (int j = 0; j < 8; ++j) u[j] = f2bf(acc[i][j]);
            *(uint4*)dst = *(uint4*)u;
        }
    }
}

// LSTM v2 (R16-proven): 128n x 128jp block, 4 waves (2x2), 4x4 frags of
// 16x16x32 MFMA; epilogue in two jp-halves; fused transposed maps write.
__global__ __launch_bounds__(256) void k_lstm(const ushort* __restrict__ reg16,
                                              const ushort* __restrict__ hb16in,
                                              const ushort* __restrict__ Wt,
                                              const float* __restrict__ bc,
                                              ushort* __restrict__ hb16out,
                                              float* __restrict__ cst,
                                              float* __restrict__ out, int t) {
    __shared__ float gsm[128][68];
    __shared__ float h2sm[128][17];
    const int tid = threadIdx.x;
    const int wave = tid >> 6, lane = tid & 63;
    const int wm = wave >> 1, wn = wave & 1;
    const int n0 = blockIdx.x * 128;
    const int jp0 = blockIdx.y * 128;
    const int lr = lane & 15;
    const int lk = (lane >> 4) * 8;

    f32x4 acc[4][4];
    #pragma unroll
    for (int fm = 0; fm < 4; ++fm)
        #pragma unroll
        for (int fn = 0; fn < 4; ++fn) acc[fm][fn] = (f32x4){0.f, 0.f, 0.f, 0.f};

    size_t aoff[4];
    #pragma unroll
    for (int fm = 0; fm < 4; ++fm) {
        int n = n0 + wm * 64 + fm * 16 + lr;
        aoff[fm] = (size_t)((n < NROWS) ? n : (NROWS - 1)) * EE;
    }
    size_t boff[4];
    #pragma unroll
    for (int fn = 0; fn < 4; ++fn)
        boff[fn] = (size_t)(jp0 + wn * 64 + fn * 16 + lr) * 256;

    for (int ks = 0; ks < 8; ++ks) {     // not unrolled (VGPR guard)
        const ushort* src = (ks < 4) ? reg16 : hb16in;
        const int koff = ((ks < 4) ? ks : (ks - 4)) * 32 + lk;
        short8v a[4], bv[4];
        #pragma unroll
        for (int fm = 0; fm < 4; ++fm) a[fm] = *(const short8v*)(src + aoff[fm] + koff);
        #pragma unroll
        for (int fn = 0; fn < 4; ++fn) bv[fn] = *(const short8v*)(Wt + boff[fn] + ks * 32 + lk);
        #pragma unroll
        for (int fm = 0; fm < 4; ++fm)
            #pragma unroll
            for (int fn = 0; fn < 4; ++fn)
                acc[fm][fn] = __builtin_amdgcn_mfma_f32_16x16x32_bf16(a[fm], bv[fn], acc[fm][fn], 0, 0, 0);
    }

    #pragma unroll
    for (int half = 0; half < 2; ++half) {
        if (wn == half) {
            #pragma unroll
            for (int fm = 0; fm < 4; ++fm)
                #pragma unroll
                for (int fn = 0; fn < 4; ++fn)
                    #pragma unroll
                    for (int r = 0; r < 4; ++r)
                        gsm[wm * 64 + fm * 16 + (lane >> 4) * 4 + r]
                           [fn * 16 + (lane & 15)] = acc[fm][fn][r];
        }
        __syncthreads();

        const int jph0 = jp0 + half * 64;
        const int jjl = tid & 15;
        const int jj = (jph0 >> 2) + jjl;
        const float4 bvv = *(const float4*)(bc + jph0 + jjl * 4);
        for (int i = 0; i < 8; ++i) {
            int nrel = (tid >> 4) * 8 + i;
            int n = n0 + nrel;
            float4 g = *(const float4*)&gsm[nrel][jjl * 4];
            float h2 = 0.f;
            if (n < NROWS) {
                float gi = g.x + bvv.x, gf = g.y + bvv.y, gg = g.z + bvv.z, go = g.w + bvv.w;
                size_t off = (size_t)n * EE + jj;
                float cv = cst[off];
                float c2 = sigf(gf) * cv + sigf(gi) * tanhf(gg);
                h2 = sigf(go) * tanhf(c2);
                cst[off] = c2;
                hb16out[off] = f2bf(h2);
            }
            h2sm[nrel][jjl] = h2;
        }
        __syncthreads();

        const int nrel2 = tid & 127;
        const int n2 = n0 + nrel2;
        if (n2 < NROWS) {
            const int b2 = n2 / PP, p2 = n2 - b2 * PP;
            const size_t base = MAPS_OFF + ((size_t)(b2 * NSTEP + t) * EE) * PP + p2;
            #pragma unroll
            for (int pass = 0; pass < 8; ++pass) {
                int jl = pass * 2 + (tid >> 7);
                out[base + (size_t)((jph0 >> 2) + jl) * PP] = h2sm[nrel2][jl];
            }
        }
        __syncthreads();
    }
}

// wprep: wT16[b][o][tap][e] = bf16( rot_o(img[b,t+1])[e][tap] )
__global__ __launch_bounds__(256) void k_wprep(const float* __restrict__ images,
                                               ushort* __restrict__ wT16, int t) {
    __shared__ float img_s[64][225];
    const int eh = blockIdx.x;
    const int o  = blockIdx.y;
    const int b  = blockIdx.z;
    const int tid = threadIdx.x;
    const float* img = images + ((size_t)(b * TT + t + 1) * EE + eh * 64) * 225;
    for (int i = tid; i < 64 * 225; i += 256)
        img_s[i / 225][i % 225] = img[i];
    __syncthreads();
    ushort* w = wT16 + ((size_t)(b * OO + o) * 225) * EE + eh * 64;
    for (int j = tid; j < 225 * 64; j += 256) {
        int tap = j >> 6, el = j & 63;
        int r = tap / 15, c = tap - r * 15;
        w[(size_t)tap * EE + el] = f2bf(img_s[el][rotoff(o, r, c)]);
    }
}

// localize v9 (R15/R16-proven): dy-thirds in grid, 52.5 KB LDS slab,
// 3 blocks/CU; 256 thr = 4 waves = o; lane = e-pair, packed dot2;
// no launch_bounds cap, dyl loop not unrolled. rawp: [dyt=3][b][o][729].
__global__ __launch_bounds__(256) void k_localize(const ushort* __restrict__ h16,
                                                  const ushort* __restrict__ wT16,
                                                  float* __restrict__ rawp) {
    __shared__ ushort tile[5 * MM * EE];   // 52,480 B
    const int y   = blockIdx.x;            // 0..26
    const int b   = blockIdx.y;
    const int dyt = blockIdx.z;            // 0..2
    const int tid = threadIdx.x;
    const int o    = tid >> 6;             // wave = orientation
    const int lane = tid & 63;             // e-pair index
    const int dy0 = dyt * 5;

    const uint4* s4 = (const uint4*)(h16 + ((size_t)b * PP + (size_t)(y + dy0) * MM) * EE);
    uint4* d4 = (uint4*)tile;
    for (int i = tid; i < 3280; i += 256) d4[i] = s4[i];
    __syncthreads();

    float acc[SS];
    #pragma unroll
    for (int x = 0; x < SS; ++x) acc[x] = 0.f;

    const uint* tl = (const uint*)tile + lane;
    const uint* wo = (const uint*)(wT16 + (((size_t)b * OO + o) * 225) * EE) + lane;

    for (int dyl = 0; dyl < 5; ++dyl) {    // NOT unrolled (spill guard)
        uint hrow[MM];
        const uint* tr = tl + (size_t)dyl * MM * 64;
        #pragma unroll
        for (int c = 0; c < MM; ++c) hrow[c] = tr[c * 64];
        const uint* wd = wo + (size_t)((dy0 + dyl) * 15) * 64;
        #pragma unroll
        for (int dx = 0; dx < 15; ++dx) {
            uint uw = wd[dx * 64];
#if __has_builtin(__builtin_amdgcn_fdot2_f32_bf16)
            bf16x2 w2 = __builtin_bit_cast(bf16x2, uw);
            #pragma unroll
            for (int x = 0; x < SS; ++x)
                acc[x] = __builtin_amdgcn_fdot2_f32_bf16(
                    __builtin_bit_cast(bf16x2, hrow[x + dx]), w2, acc[x], false);
#else
            float wl = bf2f((ushort)(uw & 0xffffu));
            float wh = bf2f((ushort)(uw >> 16));
            #pragma unroll
            for (int x = 0; x < SS; ++x) {
                uint hu = hrow[x + dx];
                acc[x] += bf2f((ushort)(hu & 0xffffu)) * wl
                        + bf2f((ushort)(hu >> 16)) * wh;
            }
#endif
        }
    }

    #pragma unroll
    for (int x = 0; x < SS; ++x) {
        float v = acc[x];
        v += __shfl_xor(v, 1);  v += __shfl_xor(v, 2);  v += __shfl_xor(v, 4);
        v += __shfl_xor(v, 8);  v += __shfl_xor(v, 16); v += __shfl_xor(v, 32);
        if (lane == 0)
            rawp[(((size_t)dyt * BB + b) * OO + o) * (SS * SS) + y * SS + x] = v;
    }
}

__global__ __launch_bounds__(256) void k_softmax(const float* __restrict__ rawp,
                                                 float* __restrict__ out,
                                                 ushort* __restrict__ pose16, int t) {
    const int b = blockIdx.x, tid = threadIdx.x;
    const int NTOT = OO * SS * SS;
    __shared__ float sv[OO * SS * SS];
    __shared__ float red[256];

    const float* p0 = rawp + (size_t)b * NTOT;
    for (int i = tid; i < NTOT; i += 256) {
        float s = 0.f;
        #pragma unroll
        for (int q = 0; q < NPS; ++q) s += p0[(size_t)q * BB * NTOT + i];
        sv[i] = s;
    }
    __syncthreads();

    float mx = -3.4e38f;
    for (int i = tid; i < NTOT; i += 256) mx = fmaxf(mx, sv[i]);
    red[tid] = mx; __syncthreads();
    for (int s = 128; s > 0; s >>= 1) {
        if (tid < s) red[tid] = fmaxf(red[tid], red[tid + s]);
        __syncthreads();
    }
    mx = red[0]; __syncthreads();

    float sm = 0.f;
    for (int i = tid; i < NTOT; i += 256) sm += expf(sv[i] - mx);
    red[tid] = sm; __syncthreads();
    for (int s = 128; s > 0; s >>= 1) {
        if (tid < s) red[tid] += red[tid + s];
        __syncthreads();
    }
    const float inv = 1.f / red[0];

    float* rawOut = out + RAWS_OFF + ((size_t)(b * NSTEP + t) * OO) * PP;
    float* spOut  = out + SPS_OFF  + ((size_t)(b * NSTEP + t) * OO) * PP;
    ushort* pb = pose16 + (size_t)b * OO * MM * MM;
    for (int i = tid; i < OO * MM * MM; i += 256) {
        int o = i / (MM * MM), rem = i % (MM * MM), yy = rem / MM - VR, xx = rem % MM - VR;
        float rv = 0.f, sv2 = 0.f;
        if ((unsigned)yy < SS && (unsigned)xx < SS) {
            float r = sv[(o * SS + yy) * SS + xx];
            rv = r;
            sv2 = expf(r - mx) * inv;
        }
        rawOut[i] = rv;
        spOut[i] = sv2;
        pb[i] = f2bf(sv2);
    }
}

extern "C" void kernel_launch(void* const* d_in, const int* in_sizes, int n_in,
                              void* d_out, int out_size, void* d_ws, size_t ws_size,
                              hipStream_t stream) {
    const float* images = (const float*)d_in[0];
    const float* wih    = (const float*)d_in[1];
    const float* whh    = (const float*)d_in[2];
    const float* bih    = (const float*)d_in[3];
    const float* bhh    = (const float*)d_in[4];
    float* out = (float*)d_out;
    float* ws  = (float*)d_ws;

    // layout (float units), total ~10.5M floats = 42 MB
    ushort* pose16 = (ushort*)ws;                         // 107,584 u16 (53,792 fl)
    float*  cst   = ws + 107584;                          // 3,442,688 fp32 (keeps old offset; pose slack unused)
    ushort* hbA   = (ushort*)(cst + 3442688);             // 1,721,344 float-slots
    ushort* hbB   = (ushort*)(cst + 3442688 + 1721344);   // 1,721,344 float-slots
    float*  regbF = cst + 3442688 + 2 * 1721344;          // 3,442,688 region
    ushort* reg16 = (ushort*)regbF;                       // bf16 reg
    // aliases inside regb region (dead between k_lstm(t) and k_register(t+1)):
    float*  rawp  = regbF;                                // 139,968 floats (NPS=3)
    ushort* wT16  = (ushort*)(regbF + 262144);            // 921,600 float-slots
    ushort* Wt    = (ushort*)(regbF + 3442688);           // 65,536 float-slots
    float*  bc    = regbF + 3442688 + 65536;              // 512

    hipMemsetAsync(hbA, 0, (size_t)1721344 * 4, stream);
    hipMemsetAsync(cst, 0, (size_t)3442688 * 4, stream);
    k_init<<<421, 256, 0, stream>>>(pose16);
    k_prep<<<512, 256, 0, stream>>>(wih, whh, bih, bhh, Wt, bc);

    ushort* hbin = hbA;
    ushort* hbout = hbB;
    for (int t = 0; t < NSTEP; ++t) {
        k_register<<<dim3(7, 4, BB), 256, 0, stream>>>(images, pose16, reg16, t);
        k_lstm<<<dim3(211, 4), 256, 0, stream>>>(reg16, hbin, Wt, bc, hbout, cst, out, t);
        k_wprep<<<dim3(2, OO, BB), 256, 0, stream>>>(images, wT16, t);
        k_localize<<<dim3(SS, BB, 3), 256, 0, stream>>>(hbout, wT16, rawp);
        k_softmax<<<BB, 256, 0, stream>>>(rawp, out, pose16, t);
        ushort* tmp = hbin; hbin = hbout; hbout = tmp;
    }
}

// Round 20
// 2888.508 us; speedup vs baseline: 1.3435x; 1.3435x over previous
//
#include <hip/hip_runtime.h>
#include <math.h>

#define BB 16
#define TT 16
#define EE 128
#define KS 15
#define MM 41
#define OO 4
#define VR 7
#define SS 27
#define NSTEP 15
#define PP (MM*MM)
#define NROWS (BB*PP)

#define RAWS_OFF 0
#define SPS_OFF  1613760
#define MAPS_OFF 3227520

#define PM 55
#define PMSZ (PM*PM)
#define NPS 3
#define WS 34              // wsm16 row stride (u16): word-stride 17, conflict-free

typedef __attribute__((ext_vector_type(8))) short short8v;
typedef __attribute__((ext_vector_type(4))) float f32x4;
typedef __attribute__((ext_vector_type(2))) __bf16 bf16x2;
typedef unsigned short ushort;
typedef unsigned int uint;

__device__ __forceinline__ float sigf(float x) { return 1.f / (1.f + expf(-x)); }

__device__ __forceinline__ ushort f2bf(float x) {
    unsigned int u = __float_as_uint(x);
    u += 0x7FFF + ((u >> 16) & 1);
    return (ushort)(u >> 16);
}
__device__ __forceinline__ float bf2f(ushort u) {
    return __uint_as_float((unsigned int)u << 16);
}

__device__ __forceinline__ int rotoff(int o, int r, int c) {
    int ir, ic;
    if (o == 0)      { ir = r;      ic = c;      }
    else if (o == 1) { ir = c;      ic = 14 - r; }
    else if (o == 2) { ir = 14 - r; ic = 14 - c; }
    else             { ir = 14 - c; ic = r;      }
    return ir * 15 + ic;
}

__global__ void k_init(float* __restrict__ pose) {
    int idx = blockIdx.x * 256 + threadIdx.x;
    if (idx < BB * OO * MM * MM) {
        int r = idx % (OO * MM * MM);
        pose[idx] = (r == (20 * MM + 20)) ? 1.f : 0.f;
    }
}

// Wt[jp][k] bf16 (B^T layout for MFMA), jp = jj*4+g; bc[jp] = bih+bhh
__global__ void k_prep(const float* __restrict__ wih, const float* __restrict__ whh,
                       const float* __restrict__ bih, const float* __restrict__ bhh,
                       ushort* __restrict__ Wt, float* __restrict__ bc) {
    int idx = blockIdx.x * 256 + threadIdx.x;   // [0, 512*256)
    int jp = idx >> 8, k = idx & 255;
    int jj = jp >> 2, g = jp & 3, j = g * 128 + jj;
    float v = (k < 128) ? wih[j * 128 + k] : whh[j * 128 + (k - 128)];
    Wt[(size_t)jp * 256 + k] = f2bf(v);
    if (idx < 512) {
        int jj2 = idx >> 2, g2 = idx & 3, j2 = g2 * 128 + jj2;
        bc[idx] = bih[j2] + bhh[j2];
    }
}

// register v3: pose stays FP32 in LDS (zero-conversion hot-path reads — the
// R19 u16-pose version added a shift to all 16 per-tap reads and LOST 71 µs).
// Only weights go bf16: wsm16[225*34] = 15.3 KB, staging word-stride 17 ->
// conflict-free (old fp32 stride-36 layout cost 9.5M conflict cycles);
// per-tap unpack (4 uint loads + 8 shifts) is WAVE-UNIFORM, amortized over
// 128 FMAs. LDS 80.9 -> 63.7 KB -> 2 blocks/CU. Index math R4-verified.
__global__ __launch_bounds__(256) void k_register(const float* __restrict__ images,
                                                  const float* __restrict__ pose,
                                                  ushort* __restrict__ reg16, int t) {
    __shared__ float ps[OO * PMSZ];      // 48.4 KB
    __shared__ ushort wsm16[225 * WS];   // 15.3 KB
    const int p0 = blockIdx.x * 256;
    const int eq = blockIdx.y;
    const int b  = blockIdx.z;
    const int tid = threadIdx.x;

    for (int i = tid; i < OO * PMSZ; i += 256) {
        int o = i / PMSZ, rem = i % PMSZ, r = rem / PM, c = rem % PM;
        float v = 0.f;
        if (r >= VR && r < VR + MM && c >= VR && c < VR + MM)
            v = pose[(((size_t)b * OO + o) * MM + (r - VR)) * MM + (c - VR)];
        ps[i] = v;
    }
    const float* img = images + ((size_t)(b * TT + t) * EE + eq * 32) * 225;
    for (int i = tid; i < 32 * 225; i += 256) {
        int e = i / 225, k = i - e * 225;   // consecutive tid -> consecutive k (coalesced)
        wsm16[k * WS + e] = f2bf(img[e * 225 + k]);
    }
    __syncthreads();

    const int px = tid & 63;
    const int ec = tid >> 6;               // wave-uniform
    int pbase[4];
    #pragma unroll
    for (int i = 0; i < 4; ++i) {
        int p = p0 + px + 64 * i;
        int pc = (p < PP) ? p : 0;
        int y = pc / MM, x = pc - y * MM;
        pbase[i] = (y + 2 * VR) * PM + (x + 2 * VR);
    }

    float acc[4][8];
    #pragma unroll
    for (int i = 0; i < 4; ++i)
        #pragma unroll
        for (int j = 0; j < 8; ++j) acc[i][j] = 0.f;

    for (int R = 0; R < 15; ++R) {
        #pragma unroll 5
        for (int C = 0; C < 15; ++C) {
            const ushort* wrow = &wsm16[(R * 15 + C) * WS + ec * 8];
            uint w01 = *(const uint*)(wrow);       // byte off 68*tap+16*ec: 4B-aligned
            uint w23 = *(const uint*)(wrow + 2);
            uint w45 = *(const uint*)(wrow + 4);
            uint w67 = *(const uint*)(wrow + 6);
            float w[8];
            w[0] = bf2f((ushort)(w01 & 0xffffu)); w[1] = bf2f((ushort)(w01 >> 16));
            w[2] = bf2f((ushort)(w23 & 0xffffu)); w[3] = bf2f((ushort)(w23 >> 16));
            w[4] = bf2f((ushort)(w45 & 0xffffu)); w[5] = bf2f((ushort)(w45 >> 16));
            w[6] = bf2f((ushort)(w67 & 0xffffu)); w[7] = bf2f((ushort)(w67 >> 16));
            #pragma unroll
            for (int i = 0; i < 4; ++i) {
                float a0 = ps[0 * PMSZ + pbase[i] - R * PM - C];
                float a1 = ps[1 * PMSZ + pbase[i] + (C - 14) * PM - R];
                float a2 = ps[2 * PMSZ + pbase[i] + (R - 14) * PM + (C - 14)];
                float a3 = ps[3 * PMSZ + pbase[i] - C * PM + (R - 14)];
                float s = (a0 + a1) + (a2 + a3);
                acc[i][0] += s * w[0]; acc[i][1] += s * w[1];
                acc[i][2] += s * w[2]; acc[i][3] += s * w[3];
                acc[i][4] += s * w[4]; acc[i][5] += s * w[5];
                acc[i][6] += s * w[6]; acc[i][7] += s * w[7];
            }
        }
    }

    #pragma unroll
    for (int i = 0; i < 4; ++i) {
        int p = p0 + px + 64 * i;
        if (p < PP) {
            ushort* dst = reg16 + ((size_t)b * PP + p) * EE + eq * 32 + ec * 8;
            ushort u[8];
            #pragma unroll
            for (int j = 0; j < 8; ++j) u[j] = f2bf(acc[i][j]);
            *(uint4*)dst = *(uint4*)u;
        }
    }
}

// LSTM v2 (R16-proven): 128n x 128jp block, 4 waves (2x2), 4x4 frags of
// 16x16x32 MFMA; epilogue in two jp-halves; fused transposed maps write.
__global__ __launch_bounds__(256) void k_lstm(const ushort* __restrict__ reg16,
                                              const ushort* __restrict__ hb16in,
                                              const ushort* __restrict__ Wt,
                                              const float* __restrict__ bc,
                                              ushort* __restrict__ hb16out,
                                              float* __restrict__ cst,
                                              float* __restrict__ out, int t) {
    __shared__ float gsm[128][68];
    __shared__ float h2sm[128][17];
    const int tid = threadIdx.x;
    const int wave = tid >> 6, lane = tid & 63;
    const int wm = wave >> 1, wn = wave & 1;
    const int n0 = blockIdx.x * 128;
    const int jp0 = blockIdx.y * 128;
    const int lr = lane & 15;
    const int lk = (lane >> 4) * 8;

    f32x4 acc[4][4];
    #pragma unroll
    for (int fm = 0; fm < 4; ++fm)
        #pragma unroll
        for (int fn = 0; fn < 4; ++fn) acc[fm][fn] = (f32x4){0.f, 0.f, 0.f, 0.f};

    size_t aoff[4];
    #pragma unroll
    for (int fm = 0; fm < 4; ++fm) {
        int n = n0 + wm * 64 + fm * 16 + lr;
        aoff[fm] = (size_t)((n < NROWS) ? n : (NROWS - 1)) * EE;
    }
    size_t boff[4];
    #pragma unroll
    for (int fn = 0; fn < 4; ++fn)
        boff[fn] = (size_t)(jp0 + wn * 64 + fn * 16 + lr) * 256;

    for (int ks = 0; ks < 8; ++ks) {     // not unrolled (VGPR guard)
        const ushort* src = (ks < 4) ? reg16 : hb16in;
        const int koff = ((ks < 4) ? ks : (ks - 4)) * 32 + lk;
        short8v a[4], bv[4];
        #pragma unroll
        for (int fm = 0; fm < 4; ++fm) a[fm] = *(const short8v*)(src + aoff[fm] + koff);
        #pragma unroll
        for (int fn = 0; fn < 4; ++fn) bv[fn] = *(const short8v*)(Wt + boff[fn] + ks * 32 + lk);
        #pragma unroll
        for (int fm = 0; fm < 4; ++fm)
            #pragma unroll
            for (int fn = 0; fn < 4; ++fn)
                acc[fm][fn] = __builtin_amdgcn_mfma_f32_16x16x32_bf16(a[fm], bv[fn], acc[fm][fn], 0, 0, 0);
    }

    #pragma unroll
    for (int half = 0; half < 2; ++half) {
        if (wn == half) {
            #pragma unroll
            for (int fm = 0; fm < 4; ++fm)
                #pragma unroll
                for (int fn = 0; fn < 4; ++fn)
                    #pragma unroll
                    for (int r = 0; r < 4; ++r)
                        gsm[wm * 64 + fm * 16 + (lane >> 4) * 4 + r]
                           [fn * 16 + (lane & 15)] = acc[fm][fn][r];
        }
        __syncthreads();

        const int jph0 = jp0 + half * 64;
        const int jjl = tid & 15;
        const int jj = (jph0 >> 2) + jjl;
        const float4 bvv = *(const float4*)(bc + jph0 + jjl * 4);
        for (int i = 0; i < 8; ++i) {
            int nrel = (tid >> 4) * 8 + i;
            int n = n0 + nrel;
            float4 g = *(const float4*)&gsm[nrel][jjl * 4];
            float h2 = 0.f;
            if (n < NROWS) {
                float gi = g.x + bvv.x, gf = g.y + bvv.y, gg = g.z + bvv.z, go = g.w + bvv.w;
                size_t off = (size_t)n * EE + jj;
                float cv = cst[off];
                float c2 = sigf(gf) * cv + sigf(gi) * tanhf(gg);
                h2 = sigf(go) * tanhf(c2);
                cst[off] = c2;
                hb16out[off] = f2bf(h2);
            }
            h2sm[nrel][jjl] = h2;
        }
        __syncthreads();

        const int nrel2 = tid & 127;
        const int n2 = n0 + nrel2;
        if (n2 < NROWS) {
            const int b2 = n2 / PP, p2 = n2 - b2 * PP;
            const size_t base = MAPS_OFF + ((size_t)(b2 * NSTEP + t) * EE) * PP + p2;
            #pragma unroll
            for (int pass = 0; pass < 8; ++pass) {
                int jl = pass * 2 + (tid >> 7);
                out[base + (size_t)((jph0 >> 2) + jl) * PP] = h2sm[nrel2][jl];
            }
        }
        __syncthreads();
    }
}

// wprep: wT16[b][o][tap][e] = bf16( rot_o(img[b,t+1])[e][tap] )
__global__ __launch_bounds__(256) void k_wprep(const float* __restrict__ images,
                                               ushort* __restrict__ wT16, int t) {
    __shared__ float img_s[64][225];
    const int eh = blockIdx.x;
    const int o  = blockIdx.y;
    const int b  = blockIdx.z;
    const int tid = threadIdx.x;
    const float* img = images + ((size_t)(b * TT + t + 1) * EE + eh * 64) * 225;
    for (int i = tid; i < 64 * 225; i += 256)
        img_s[i / 225][i % 225] = img[i];
    __syncthreads();
    ushort* w = wT16 + ((size_t)(b * OO + o) * 225) * EE + eh * 64;
    for (int j = tid; j < 225 * 64; j += 256) {
        int tap = j >> 6, el = j & 63;
        int r = tap / 15, c = tap - r * 15;
        w[(size_t)tap * EE + el] = f2bf(img_s[el][rotoff(o, r, c)]);
    }
}

// localize v9 (R15/R16-proven): dy-thirds in grid, 52.5 KB LDS slab,
// 3 blocks/CU; 256 thr = 4 waves = o; lane = e-pair, packed dot2;
// no launch_bounds cap, dyl loop not unrolled. rawp: [dyt=3][b][o][729].
__global__ __launch_bounds__(256) void k_localize(const ushort* __restrict__ h16,
                                                  const ushort* __restrict__ wT16,
                                                  float* __restrict__ rawp) {
    __shared__ ushort tile[5 * MM * EE];   // 52,480 B
    const int y   = blockIdx.x;            // 0..26
    const int b   = blockIdx.y;
    const int dyt = blockIdx.z;            // 0..2
    const int tid = threadIdx.x;
    const int o    = tid >> 6;             // wave = orientation
    const int lane = tid & 63;             // e-pair index
    const int dy0 = dyt * 5;

    const uint4* s4 = (const uint4*)(h16 + ((size_t)b * PP + (size_t)(y + dy0) * MM) * EE);
    uint4* d4 = (uint4*)tile;
    for (int i = tid; i < 3280; i += 256) d4[i] = s4[i];
    __syncthreads();

    float acc[SS];
    #pragma unroll
    for (int x = 0; x < SS; ++x) acc[x] = 0.f;

    const uint* tl = (const uint*)tile + lane;
    const uint* wo = (const uint*)(wT16 + (((size_t)b * OO + o) * 225) * EE) + lane;

    for (int dyl = 0; dyl < 5; ++dyl) {    // NOT unrolled (spill guard)
        uint hrow[MM];
        const uint* tr = tl + (size_t)dyl * MM * 64;
        #pragma unroll
        for (int c = 0; c < MM; ++c) hrow[c] = tr[c * 64];
        const uint* wd = wo + (size_t)((dy0 + dyl) * 15) * 64;
        #pragma unroll
        for (int dx = 0; dx < 15; ++dx) {
            uint uw = wd[dx * 64];
#if __has_builtin(__builtin_amdgcn_fdot2_f32_bf16)
            bf16x2 w2 = __builtin_bit_cast(bf16x2, uw);
            #pragma unroll
            for (int x = 0; x < SS; ++x)
                acc[x] = __builtin_amdgcn_fdot2_f32_bf16(
                    __builtin_bit_cast(bf16x2, hrow[x + dx]), w2, acc[x], false);
#else
            float wl = bf2f((ushort)(uw & 0xffffu));
            float wh = bf2f((ushort)(uw >> 16));
            #pragma unroll
            for (int x = 0; x < SS; ++x) {
                uint hu = hrow[x + dx];
                acc[x] += bf2f((ushort)(hu & 0xffffu)) * wl
                        + bf2f((ushort)(hu >> 16)) * wh;
            }
#endif
        }
    }

    #pragma unroll
    for (int x = 0; x < SS; ++x) {
        float v = acc[x];
        v += __shfl_xor(v, 1);  v += __shfl_xor(v, 2);  v += __shfl_xor(v, 4);
        v += __shfl_xor(v, 8);  v += __shfl_xor(v, 16); v += __shfl_xor(v, 32);
        if (lane == 0)
            rawp[(((size_t)dyt * BB + b) * OO + o) * (SS * SS) + y * SS + x] = v;
    }
}

__global__ __launch_bounds__(256) void k_softmax(const float* __restrict__ rawp,
                                                 float* __restrict__ out,
                                                 float* __restrict__ pose, int t) {
    const int b = blockIdx.x, tid = threadIdx.x;
    const int NTOT = OO * SS * SS;
    __shared__ float sv[OO * SS * SS];
    __shared__ float red[256];

    const float* p0 = rawp + (size_t)b * NTOT;
    for (int i = tid; i < NTOT; i += 256) {
        float s = 0.f;
        #pragma unroll
        for (int q = 0; q < NPS; ++q) s += p0[(size_t)q * BB * NTOT + i];
        sv[i] = s;
    }
    __syncthreads();

    float mx = -3.4e38f;
    for (int i = tid; i < NTOT; i += 256) mx = fmaxf(mx, sv[i]);
    red[tid] = mx; __syncthreads();
    for (int s = 128; s > 0; s >>= 1) {
        if (tid < s) red[tid] = fmaxf(red[tid], red[tid + s]);
        __syncthreads();
    }
    mx = red[0]; __syncthreads();

    float sm = 0.f;
    for (int i = tid; i < NTOT; i += 256) sm += expf(sv[i] - mx);
    red[tid] = sm; __syncthreads();
    for (int s = 128; s > 0; s >>= 1) {
        if (tid < s) red[tid] += red[tid + s];
        __syncthreads();
    }
    const float inv = 1.f / red[0];

    float* rawOut = out + RAWS_OFF + ((size_t)(b * NSTEP + t) * OO) * PP;
    float* spOut  = out + SPS_OFF  + ((size_t)(b * NSTEP + t) * OO) * PP;
    float* pb = pose + (size_t)b * OO * MM * MM;
    for (int i = tid; i < OO * MM * MM; i += 256) {
        int o = i / (MM * MM), rem = i % (MM * MM), yy = rem / MM - VR, xx = rem % MM - VR;
        float rv = 0.f, sv2 = 0.f;
        if ((unsigned)yy < SS && (unsigned)xx < SS) {
            float r = sv[(o * SS + yy) * SS + xx];
            rv = r;
            sv2 = expf(r - mx) * inv;
        }
        rawOut[i] = rv;
        spOut[i] = sv2;
        pb[i] = sv2;
    }
}

extern "C" void kernel_launch(void* const* d_in, const int* in_sizes, int n_in,
                              void* d_out, int out_size, void* d_ws, size_t ws_size,
                              hipStream_t stream) {
    const float* images = (const float*)d_in[0];
    const float* wih    = (const float*)d_in[1];
    const float* whh    = (const float*)d_in[2];
    const float* bih    = (const float*)d_in[3];
    const float* bhh    = (const float*)d_in[4];
    float* out = (float*)d_out;
    float* ws  = (float*)d_ws;

    // layout (float units), total ~10.5M floats = 42 MB
    float*  pose  = ws;                                   // 107,584
    float*  cst   = pose + 107584;                        // 3,442,688 fp32
    ushort* hbA   = (ushort*)(cst + 3442688);             // 1,721,344 float-slots
    ushort* hbB   = (ushort*)(cst + 3442688 + 1721344);   // 1,721,344 float-slots
    float*  regbF = cst + 3442688 + 2 * 1721344;          // 3,442,688 region
    ushort* reg16 = (ushort*)regbF;                       // bf16 reg
    // aliases inside regb region (dead between k_lstm(t) and k_register(t+1)):
    float*  rawp  = regbF;                                // 139,968 floats (NPS=3)
    ushort* wT16  = (ushort*)(regbF + 262144);            // 921,600 float-slots
    ushort* Wt    = (ushort*)(regbF + 3442688);           // 65,536 float-slots
    float*  bc    = regbF + 3442688 + 65536;              // 512

    hipMemsetAsync(hbA, 0, (size_t)1721344 * 4, stream);
    hipMemsetAsync(cst, 0, (size_t)3442688 * 4, stream);
    k_init<<<421, 256, 0, stream>>>(pose);
    k_prep<<<512, 256, 0, stream>>>(wih, whh, bih, bhh, Wt, bc);

    ushort* hbin = hbA;
    ushort* hbout = hbB;
    for (int t = 0; t < NSTEP; ++t) {
        k_register<<<dim3(7, 4, BB), 256, 0, stream>>>(images, pose, reg16, t);
        k_lstm<<<dim3(211, 4), 256, 0, stream>>>(reg16, hbin, Wt, bc, hbout, cst, out, t);
        k_wprep<<<dim3(2, OO, BB), 256, 0, stream>>>(images, wT16, t);
        k_localize<<<dim3(SS, BB, 3), 256, 0, stream>>>(hbout, wT16, rawp);
        k_softmax<<<BB, 256, 0, stream>>>(rawp, out, pose, t);
        ushort* tmp = hbin; hbin = hbout; hbout = tmp;
    }
}

// Round 21
// 2177.040 us; speedup vs baseline: 1.7826x; 1.3268x over previous
//
#include <hip/hip_runtime.h>
#include <math.h>

#define BB 16
#define TT 16
#define EE 128
#define KS 15
#define MM 41
#define OO 4
#define VR 7
#define SS 27
#define NSTEP 15
#define PP (MM*MM)
#define NROWS (BB*PP)

#define RAWS_OFF 0
#define SPS_OFF  1613760
#define MAPS_OFF 3227520

#define PM 55
#define PMSZ (PM*PM)
#define NPS 3

typedef __attribute__((ext_vector_type(8))) short short8v;
typedef __attribute__((ext_vector_type(4))) float f32x4;
typedef __attribute__((ext_vector_type(2))) __bf16 bf16x2;
typedef unsigned short ushort;
typedef unsigned int uint;

__device__ __forceinline__ float sigf(float x) { return 1.f / (1.f + expf(-x)); }

__device__ __forceinline__ ushort f2bf(float x) {
    unsigned int u = __float_as_uint(x);
    u += 0x7FFF + ((u >> 16) & 1);
    return (ushort)(u >> 16);
}
__device__ __forceinline__ float bf2f(ushort u) {
    return __uint_as_float((unsigned int)u << 16);
}

__device__ __forceinline__ int rotoff(int o, int r, int c) {
    int ir, ic;
    if (o == 0)      { ir = r;      ic = c;      }
    else if (o == 1) { ir = c;      ic = 14 - r; }
    else if (o == 2) { ir = 14 - r; ic = 14 - c; }
    else             { ir = 14 - c; ic = r;      }
    return ir * 15 + ic;
}

__global__ void k_init(float* __restrict__ pose) {
    int idx = blockIdx.x * 256 + threadIdx.x;
    if (idx < BB * OO * MM * MM) {
        int r = idx % (OO * MM * MM);
        pose[idx] = (r == (20 * MM + 20)) ? 1.f : 0.f;
    }
}

// Wt[jp][k] bf16 (B^T layout for MFMA), jp = jj*4+g; bc[jp] = bih+bhh
__global__ void k_prep(const float* __restrict__ wih, const float* __restrict__ whh,
                       const float* __restrict__ bih, const float* __restrict__ bhh,
                       ushort* __restrict__ Wt, float* __restrict__ bc) {
    int idx = blockIdx.x * 256 + threadIdx.x;   // [0, 512*256)
    int jp = idx >> 8, k = idx & 255;
    int jj = jp >> 2, g = jp & 3, j = g * 128 + jj;
    float v = (k < 128) ? wih[j * 128 + k] : whh[j * 128 + (k - 128)];
    Wt[(size_t)jp * 256 + k] = f2bf(v);
    if (idx < 512) {
        int jj2 = idx >> 2, g2 = idx & 3, j2 = g2 * 128 + jj2;
        bc[idx] = bih[j2] + bhh[j2];
    }
}

// register v4: im2col-fused MFMA GEMM.
//   reg[p][e] = sum_k q[p][k] * img[e][k],   q[p][k] = sum_o ps[f_o(p,k)]
// A-fragments built IN-REGISTER from pose LDS gathers — each (p,tap,o) read
// exactly once for ALL 128 e (v1 re-gathered 4x, once per eq quarter: 14.4M
// ds_read -> 1.8M). B-fragments from global fp32 img (scalar loads; 225-float
// rows are not 16B aligned), f2bf in-register. K padded to 256 (taps>=225 -> 0).
// Block = 64p x 128e, 4 waves (2m x 2n); frag layouts mirror k_lstm (verified).
// LDS = pose only (48.4 KB) -> 3 blocks/CU. Offsets per tap shared across fm.
__global__ __launch_bounds__(256) void k_register(const float* __restrict__ images,
                                                  const float* __restrict__ pose,
                                                  ushort* __restrict__ reg16, int t) {
    __shared__ float ps[OO * PMSZ];      // 48.4 KB
    const int p0 = blockIdx.x * 64;
    const int b  = blockIdx.y;
    const int tid = threadIdx.x;

    for (int i = tid; i < OO * PMSZ; i += 256) {
        int o = i / PMSZ, rem = i % PMSZ, r = rem / PM, c = rem % PM;
        float v = 0.f;
        if (r >= VR && r < VR + MM && c >= VR && c < VR + MM)
            v = pose[(((size_t)b * OO + o) * MM + (r - VR)) * MM + (c - VR)];
        ps[i] = v;
    }
    __syncthreads();

    const int wave = tid >> 6, lane = tid & 63;
    const int wm = wave >> 1, wn = wave & 1;
    const int lr = lane & 15;
    const int lk = (lane >> 4) * 8;

    int pbase[2];
    #pragma unroll
    for (int fm = 0; fm < 2; ++fm) {
        int p = p0 + wm * 32 + fm * 16 + lr;
        int pc = (p < PP) ? p : 0;
        int y = pc / MM, x = pc - y * MM;
        pbase[fm] = (y + 2 * VR) * PM + (x + 2 * VR);
    }
    const float* imgb = images + ((size_t)(b * TT + t) * EE) * 225;

    f32x4 acc[2][4];
    #pragma unroll
    for (int fm = 0; fm < 2; ++fm)
        #pragma unroll
        for (int fn = 0; fn < 4; ++fn) acc[fm][fn] = (f32x4){0.f, 0.f, 0.f, 0.f};

    for (int ks = 0; ks < 8; ++ks) {     // not unrolled (VGPR guard)
        // ---- A-frags: gather q for this lane's 8 taps, both fm rows ----
        ushort ua[2][8];
        #pragma unroll
        for (int j = 0; j < 8; ++j) {
            int k = ks * 32 + lk + j;
            int kk = (k < 225) ? k : 0;
            int R = kk / 15, C = kk - R * 15;
            int o0 = -R * PM - C;
            int o1 = (C - 14) * PM - R;
            int o2 = (R - 14) * PM + (C - 14);
            int o3 = -C * PM + (R - 14);
            #pragma unroll
            for (int fm = 0; fm < 2; ++fm) {
                float s = 0.f;
                if (k < 225) {
                    float a0 = ps[0 * PMSZ + pbase[fm] + o0];
                    float a1 = ps[1 * PMSZ + pbase[fm] + o1];
                    float a2 = ps[2 * PMSZ + pbase[fm] + o2];
                    float a3 = ps[3 * PMSZ + pbase[fm] + o3];
                    s = (a0 + a1) + (a2 + a3);
                }
                ua[fm][j] = f2bf(s);
            }
        }
        short8v a0v = *(short8v*)ua[0];
        short8v a1v = *(short8v*)ua[1];

        // ---- B-frags: img[e][k-chunk] fp32 -> bf16 (scalar loads) ----
        short8v bv[4];
        #pragma unroll
        for (int fn = 0; fn < 4; ++fn) {
            int e = wn * 64 + fn * 16 + lr;
            const float* ib = imgb + (size_t)e * 225;
            ushort u[8];
            #pragma unroll
            for (int j = 0; j < 8; ++j) {
                int k = ks * 32 + lk + j;
                u[j] = (k < 225) ? f2bf(ib[k]) : (ushort)0;
            }
            bv[fn] = *(short8v*)u;
        }

        acc[0][0] = __builtin_amdgcn_mfma_f32_16x16x32_bf16(a0v, bv[0], acc[0][0], 0, 0, 0);
        acc[0][1] = __builtin_amdgcn_mfma_f32_16x16x32_bf16(a0v, bv[1], acc[0][1], 0, 0, 0);
        acc[0][2] = __builtin_amdgcn_mfma_f32_16x16x32_bf16(a0v, bv[2], acc[0][2], 0, 0, 0);
        acc[0][3] = __builtin_amdgcn_mfma_f32_16x16x32_bf16(a0v, bv[3], acc[0][3], 0, 0, 0);
        acc[1][0] = __builtin_amdgcn_mfma_f32_16x16x32_bf16(a1v, bv[0], acc[1][0], 0, 0, 0);
        acc[1][1] = __builtin_amdgcn_mfma_f32_16x16x32_bf16(a1v, bv[1], acc[1][1], 0, 0, 0);
        acc[1][2] = __builtin_amdgcn_mfma_f32_16x16x32_bf16(a1v, bv[2], acc[1][2], 0, 0, 0);
        acc[1][3] = __builtin_amdgcn_mfma_f32_16x16x32_bf16(a1v, bv[3], acc[1][3], 0, 0, 0);
    }

    // epilogue: C col = lane&15 (e), row = (lane>>4)*4 + r (p)  [m89-verified]
    #pragma unroll
    for (int fm = 0; fm < 2; ++fm) {
        #pragma unroll
        for (int r4 = 0; r4 < 4; ++r4) {
            int p = p0 + wm * 32 + fm * 16 + (lane >> 4) * 4 + r4;
            if (p < PP) {
                ushort* dst = reg16 + ((size_t)b * PP + p) * EE;
                #pragma unroll
                for (int fn = 0; fn < 4; ++fn) {
                    int e = wn * 64 + fn * 16 + (lane & 15);
                    dst[e] = f2bf(acc[fm][fn][r4]);
                }
            }
        }
    }
}

// LSTM v2 (R16-proven): 128n x 128jp block, 4 waves (2x2), 4x4 frags of
// 16x16x32 MFMA; epilogue in two jp-halves; fused transposed maps write.
__global__ __launch_bounds__(256) void k_lstm(const ushort* __restrict__ reg16,
                                              const ushort* __restrict__ hb16in,
                                              const ushort* __restrict__ Wt,
                                              const float* __restrict__ bc,
                                              ushort* __restrict__ hb16out,
                                              float* __restrict__ cst,
                                              float* __restrict__ out, int t) {
    __shared__ float gsm[128][68];
    __shared__ float h2sm[128][17];
    const int tid = threadIdx.x;
    const int wave = tid >> 6, lane = tid & 63;
    const int wm = wave >> 1, wn = wave & 1;
    const int n0 = blockIdx.x * 128;
    const int jp0 = blockIdx.y * 128;
    const int lr = lane & 15;
    const int lk = (lane >> 4) * 8;

    f32x4 acc[4][4];
    #pragma unroll
    for (int fm = 0; fm < 4; ++fm)
        #pragma unroll
        for (int fn = 0; fn < 4; ++fn) acc[fm][fn] = (f32x4){0.f, 0.f, 0.f, 0.f};

    size_t aoff[4];
    #pragma unroll
    for (int fm = 0; fm < 4; ++fm) {
        int n = n0 + wm * 64 + fm * 16 + lr;
        aoff[fm] = (size_t)((n < NROWS) ? n : (NROWS - 1)) * EE;
    }
    size_t boff[4];
    #pragma unroll
    for (int fn = 0; fn < 4; ++fn)
        boff[fn] = (size_t)(jp0 + wn * 64 + fn * 16 + lr) * 256;

    for (int ks = 0; ks < 8; ++ks) {     // not unrolled (VGPR guard)
        const ushort* src = (ks < 4) ? reg16 : hb16in;
        const int koff = ((ks < 4) ? ks : (ks - 4)) * 32 + lk;
        short8v a[4], bv[4];
        #pragma unroll
        for (int fm = 0; fm < 4; ++fm) a[fm] = *(const short8v*)(src + aoff[fm] + koff);
        #pragma unroll
        for (int fn = 0; fn < 4; ++fn) bv[fn] = *(const short8v*)(Wt + boff[fn] + ks * 32 + lk);
        #pragma unroll
        for (int fm = 0; fm < 4; ++fm)
            #pragma unroll
            for (int fn = 0; fn < 4; ++fn)
                acc[fm][fn] = __builtin_amdgcn_mfma_f32_16x16x32_bf16(a[fm], bv[fn], acc[fm][fn], 0, 0, 0);
    }

    #pragma unroll
    for (int half = 0; half < 2; ++half) {
        if (wn == half) {
            #pragma unroll
            for (int fm = 0; fm < 4; ++fm)
                #pragma unroll
                for (int fn = 0; fn < 4; ++fn)
                    #pragma unroll
                    for (int r = 0; r < 4; ++r)
                        gsm[wm * 64 + fm * 16 + (lane >> 4) * 4 + r]
                           [fn * 16 + (lane & 15)] = acc[fm][fn][r];
        }
        __syncthreads();

        const int jph0 = jp0 + half * 64;
        const int jjl = tid & 15;
        const int jj = (jph0 >> 2) + jjl;
        const float4 bvv = *(const float4*)(bc + jph0 + jjl * 4);
        for (int i = 0; i < 8; ++i) {
            int nrel = (tid >> 4) * 8 + i;
            int n = n0 + nrel;
            float4 g = *(const float4*)&gsm[nrel][jjl * 4];
            float h2 = 0.f;
            if (n < NROWS) {
                float gi = g.x + bvv.x, gf = g.y + bvv.y, gg = g.z + bvv.z, go = g.w + bvv.w;
                size_t off = (size_t)n * EE + jj;
                float cv = cst[off];
                float c2 = sigf(gf) * cv + sigf(gi) * tanhf(gg);
                h2 = sigf(go) * tanhf(c2);
                cst[off] = c2;
                hb16out[off] = f2bf(h2);
            }
            h2sm[nrel][jjl] = h2;
        }
        __syncthreads();

        const int nrel2 = tid & 127;
        const int n2 = n0 + nrel2;
        if (n2 < NROWS) {
            const int b2 = n2 / PP, p2 = n2 - b2 * PP;
            const size_t base = MAPS_OFF + ((size_t)(b2 * NSTEP + t) * EE) * PP + p2;
            #pragma unroll
            for (int pass = 0; pass < 8; ++pass) {
                int jl = pass * 2 + (tid >> 7);
                out[base + (size_t)((jph0 >> 2) + jl) * PP] = h2sm[nrel2][jl];
            }
        }
        __syncthreads();
    }
}

// wprep: wT16[b][o][tap][e] = bf16( rot_o(img[b,t+1])[e][tap] )
__global__ __launch_bounds__(256) void k_wprep(const float* __restrict__ images,
                                               ushort* __restrict__ wT16, int t) {
    __shared__ float img_s[64][225];
    const int eh = blockIdx.x;
    const int o  = blockIdx.y;
    const int b  = blockIdx.z;
    const int tid = threadIdx.x;
    const float* img = images + ((size_t)(b * TT + t + 1) * EE + eh * 64) * 225;
    for (int i = tid; i < 64 * 225; i += 256)
        img_s[i / 225][i % 225] = img[i];
    __syncthreads();
    ushort* w = wT16 + ((size_t)(b * OO + o) * 225) * EE + eh * 64;
    for (int j = tid; j < 225 * 64; j += 256) {
        int tap = j >> 6, el = j & 63;
        int r = tap / 15, c = tap - r * 15;
        w[(size_t)tap * EE + el] = f2bf(img_s[el][rotoff(o, r, c)]);
    }
}

// localize v9 (R15/R16-proven): dy-thirds in grid, 52.5 KB LDS slab,
// 3 blocks/CU; 256 thr = 4 waves = o; lane = e-pair, packed dot2;
// no launch_bounds cap, dyl loop not unrolled. rawp: [dyt=3][b][o][729].
__global__ __launch_bounds__(256) void k_localize(const ushort* __restrict__ h16,
                                                  const ushort* __restrict__ wT16,
                                                  float* __restrict__ rawp) {
    __shared__ ushort tile[5 * MM * EE];   // 52,480 B
    const int y   = blockIdx.x;            // 0..26
    const int b   = blockIdx.y;
    const int dyt = blockIdx.z;            // 0..2
    const int tid = threadIdx.x;
    const int o    = tid >> 6;             // wave = orientation
    const int lane = tid & 63;             // e-pair index
    const int dy0 = dyt * 5;

    const uint4* s4 = (const uint4*)(h16 + ((size_t)b * PP + (size_t)(y + dy0) * MM) * EE);
    uint4* d4 = (uint4*)tile;
    for (int i = tid; i < 3280; i += 256) d4[i] = s4[i];
    __syncthreads();

    float acc[SS];
    #pragma unroll
    for (int x = 0; x < SS; ++x) acc[x] = 0.f;

    const uint* tl = (const uint*)tile + lane;
    const uint* wo = (const uint*)(wT16 + (((size_t)b * OO + o) * 225) * EE) + lane;

    for (int dyl = 0; dyl < 5; ++dyl) {    // NOT unrolled (spill guard)
        uint hrow[MM];
        const uint* tr = tl + (size_t)dyl * MM * 64;
        #pragma unroll
        for (int c = 0; c < MM; ++c) hrow[c] = tr[c * 64];
        const uint* wd = wo + (size_t)((dy0 + dyl) * 15) * 64;
        #pragma unroll
        for (int dx = 0; dx < 15; ++dx) {
            uint uw = wd[dx * 64];
#if __has_builtin(__builtin_amdgcn_fdot2_f32_bf16)
            bf16x2 w2 = __builtin_bit_cast(bf16x2, uw);
            #pragma unroll
            for (int x = 0; x < SS; ++x)
                acc[x] = __builtin_amdgcn_fdot2_f32_bf16(
                    __builtin_bit_cast(bf16x2, hrow[x + dx]), w2, acc[x], false);
#else
            float wl = bf2f((ushort)(uw & 0xffffu));
            float wh = bf2f((ushort)(uw >> 16));
            #pragma unroll
            for (int x = 0; x < SS; ++x) {
                uint hu = hrow[x + dx];
                acc[x] += bf2f((ushort)(hu & 0xffffu)) * wl
                        + bf2f((ushort)(hu >> 16)) * wh;
            }
#endif
        }
    }

    #pragma unroll
    for (int x = 0; x < SS; ++x) {
        float v = acc[x];
        v += __shfl_xor(v, 1);  v += __shfl_xor(v, 2);  v += __shfl_xor(v, 4);
        v += __shfl_xor(v, 8);  v += __shfl_xor(v, 16); v += __shfl_xor(v, 32);
        if (lane == 0)
            rawp[(((size_t)dyt * BB + b) * OO + o) * (SS * SS) + y * SS + x] = v;
    }
}

__global__ __launch_bounds__(256) void k_softmax(const float* __restrict__ rawp,
                                                 float* __restrict__ out,
                                                 float* __restrict__ pose, int t) {
    const int b = blockIdx.x, tid = threadIdx.x;
    const int NTOT = OO * SS * SS;
    __shared__ float sv[OO * SS * SS];
    __shared__ float red[256];

    const float* p0 = rawp + (size_t)b * NTOT;
    for (int i = tid; i < NTOT; i += 256) {
        float s = 0.f;
        #pragma unroll
        for (int q = 0; q < NPS; ++q) s += p0[(size_t)q * BB * NTOT + i];
        sv[i] = s;
    }
    __syncthreads();

    float mx = -3.4e38f;
    for (int i = tid; i < NTOT; i += 256) mx = fmaxf(mx, sv[i]);
    red[tid] = mx; __syncthreads();
    for (int s = 128; s > 0; s >>= 1) {
        if (tid < s) red[tid] = fmaxf(red[tid], red[tid + s]);
        __syncthreads();
    }
    mx = red[0]; __syncthreads();

    float sm = 0.f;
    for (int i = tid; i < NTOT; i += 256) sm += expf(sv[i] - mx);
    red[tid] = sm; __syncthreads();
    for (int s = 128; s > 0; s >>= 1) {
        if (tid < s) red[tid] += red[tid + s];
        __syncthreads();
    }
    const float inv = 1.f / red[0];

    float* rawOut = out + RAWS_OFF + ((size_t)(b * NSTEP + t) * OO) * PP;
    float* spOut  = out + SPS_OFF  + ((size_t)(b * NSTEP + t) * OO) * PP;
    float* pb = pose + (size_t)b * OO * MM * MM;
    for (int i = tid; i < OO * MM * MM; i += 256) {
        int o = i / (MM * MM), rem = i % (MM * MM), yy = rem / MM - VR, xx = rem % MM - VR;
        float rv = 0.f, sv2 = 0.f;
        if ((unsigned)yy < SS && (unsigned)xx < SS) {
            float r = sv[(o * SS + yy) * SS + xx];
            rv = r;
            sv2 = expf(r - mx) * inv;
        }
        rawOut[i] = rv;
        spOut[i] = sv2;
        pb[i] = sv2;
    }
}

extern "C" void kernel_launch(void* const* d_in, const int* in_sizes, int n_in,
                              void* d_out, int out_size, void* d_ws, size_t ws_size,
                              hipStream_t stream) {
    const float* images = (const float*)d_in[0];
    const float* wih    = (const float*)d_in[1];
    const float* whh    = (const float*)d_in[2];
    const float* bih    = (const float*)d_in[3];
    const float* bhh    = (const float*)d_in[4];
    float* out = (float*)d_out;
    float* ws  = (float*)d_ws;

    // layout (float units), total ~10.5M floats = 42 MB
    float*  pose  = ws;                                   // 107,584
    float*  cst   = pose + 107584;                        // 3,442,688 fp32
    ushort* hbA   = (ushort*)(cst + 3442688);             // 1,721,344 float-slots
    ushort* hbB   = (ushort*)(cst + 3442688 + 1721344);   // 1,721,344 float-slots
    float*  regbF = cst + 3442688 + 2 * 1721344;          // 3,442,688 region
    ushort* reg16 = (ushort*)regbF;                       // bf16 reg
    // aliases inside regb region (dead between k_lstm(t) and k_register(t+1)):
    float*  rawp  = regbF;                                // 139,968 floats (NPS=3)
    ushort* wT16  = (ushort*)(regbF + 262144);            // 921,600 float-slots
    ushort* Wt    = (ushort*)(regbF + 3442688);           // 65,536 float-slots
    float*  bc    = regbF + 3442688 + 65536;              // 512

    hipMemsetAsync(hbA, 0, (size_t)1721344 * 4, stream);
    hipMemsetAsync(cst, 0, (size_t)3442688 * 4, stream);
    k_init<<<421, 256, 0, stream>>>(pose);
    k_prep<<<512, 256, 0, stream>>>(wih, whh, bih, bhh, Wt, bc);

    ushort* hbin = hbA;
    ushort* hbout = hbB;
    for (int t = 0; t < NSTEP; ++t) {
        k_register<<<dim3(27, BB), 256, 0, stream>>>(images, pose, reg16, t);
        k_lstm<<<dim3(211, 4), 256, 0, stream>>>(reg16, hbin, Wt, bc, hbout, cst, out, t);
        k_wprep<<<dim3(2, OO, BB), 256, 0, stream>>>(images, wT16, t);
        k_localize<<<dim3(SS, BB, 3), 256, 0, stream>>>(hbout, wT16, rawp);
        k_softmax<<<BB, 256, 0, stream>>>(rawp, out, pose, t);
        ushort* tmp = hbin; hbin = hbout; hbout = tmp;
    }
}

// Round 22
// 2161.292 us; speedup vs baseline: 1.7956x; 1.0073x over previous
//
#include <hip/hip_runtime.h>
#include <math.h>

#define BB 16
#define TT 16
#define EE 128
#define KS 15
#define MM 41
#define OO 4
#define VR 7
#define SS 27
#define NSTEP 15
#define PP (MM*MM)
#define NROWS (BB*PP)

#define RAWS_OFF 0
#define SPS_OFF  1613760
#define MAPS_OFF 3227520

#define PM 55
#define PMSZ (PM*PM)
#define NPS 3

typedef __attribute__((ext_vector_type(8))) short short8v;
typedef __attribute__((ext_vector_type(4))) float f32x4;
typedef __attribute__((ext_vector_type(2))) __bf16 bf16x2;
typedef unsigned short ushort;
typedef unsigned int uint;

__device__ __forceinline__ float sigf(float x) { return 1.f / (1.f + expf(-x)); }

__device__ __forceinline__ ushort f2bf(float x) {
    unsigned int u = __float_as_uint(x);
    u += 0x7FFF + ((u >> 16) & 1);
    return (ushort)(u >> 16);
}
__device__ __forceinline__ float bf2f(ushort u) {
    return __uint_as_float((unsigned int)u << 16);
}

__device__ __forceinline__ int rotoff(int o, int r, int c) {
    int ir, ic;
    if (o == 0)      { ir = r;      ic = c;      }
    else if (o == 1) { ir = c;      ic = 14 - r; }
    else if (o == 2) { ir = 14 - r; ic = 14 - c; }
    else             { ir = 14 - c; ic = r;      }
    return ir * 15 + ic;
}

__global__ void k_init(float* __restrict__ pose) {
    int idx = blockIdx.x * 256 + threadIdx.x;
    if (idx < BB * OO * MM * MM) {
        int r = idx % (OO * MM * MM);
        pose[idx] = (r == (20 * MM + 20)) ? 1.f : 0.f;
    }
}

// Wt[jp][k] bf16 (B^T layout for MFMA), jp = jj*4+g; bc[jp] = bih+bhh
__global__ void k_prep(const float* __restrict__ wih, const float* __restrict__ whh,
                       const float* __restrict__ bih, const float* __restrict__ bhh,
                       ushort* __restrict__ Wt, float* __restrict__ bc) {
    int idx = blockIdx.x * 256 + threadIdx.x;   // [0, 512*256)
    int jp = idx >> 8, k = idx & 255;
    int jj = jp >> 2, g = jp & 3, j = g * 128 + jj;
    float v = (k < 128) ? wih[j * 128 + k] : whh[j * 128 + (k - 128)];
    Wt[(size_t)jp * 256 + k] = f2bf(v);
    if (idx < 512) {
        int jj2 = idx >> 2, g2 = idx & 3, j2 = g2 * 128 + jj2;
        bc[idx] = bih[j2] + bhh[j2];
    }
}

// register v4 (R21-proven): im2col-fused MFMA GEMM.
//   reg[p][e] = sum_k q[p][k] * img[e][k],   q[p][k] = sum_o ps[f_o(p,k)]
__global__ __launch_bounds__(256) void k_register(const float* __restrict__ images,
                                                  const float* __restrict__ pose,
                                                  ushort* __restrict__ reg16, int t) {
    __shared__ float ps[OO * PMSZ];      // 48.4 KB
    const int p0 = blockIdx.x * 64;
    const int b  = blockIdx.y;
    const int tid = threadIdx.x;

    for (int i = tid; i < OO * PMSZ; i += 256) {
        int o = i / PMSZ, rem = i % PMSZ, r = rem / PM, c = rem % PM;
        float v = 0.f;
        if (r >= VR && r < VR + MM && c >= VR && c < VR + MM)
            v = pose[(((size_t)b * OO + o) * MM + (r - VR)) * MM + (c - VR)];
        ps[i] = v;
    }
    __syncthreads();

    const int wave = tid >> 6, lane = tid & 63;
    const int wm = wave >> 1, wn = wave & 1;
    const int lr = lane & 15;
    const int lk = (lane >> 4) * 8;

    int pbase[2];
    #pragma unroll
    for (int fm = 0; fm < 2; ++fm) {
        int p = p0 + wm * 32 + fm * 16 + lr;
        int pc = (p < PP) ? p : 0;
        int y = pc / MM, x = pc - y * MM;
        pbase[fm] = (y + 2 * VR) * PM + (x + 2 * VR);
    }
    const float* imgb = images + ((size_t)(b * TT + t) * EE) * 225;

    f32x4 acc[2][4];
    #pragma unroll
    for (int fm = 0; fm < 2; ++fm)
        #pragma unroll
        for (int fn = 0; fn < 4; ++fn) acc[fm][fn] = (f32x4){0.f, 0.f, 0.f, 0.f};

    for (int ks = 0; ks < 8; ++ks) {     // not unrolled (VGPR guard)
        ushort ua[2][8];
        #pragma unroll
        for (int j = 0; j < 8; ++j) {
            int k = ks * 32 + lk + j;
            int kk = (k < 225) ? k : 0;
            int R = kk / 15, C = kk - R * 15;
            int o0 = -R * PM - C;
            int o1 = (C - 14) * PM - R;
            int o2 = (R - 14) * PM + (C - 14);
            int o3 = -C * PM + (R - 14);
            #pragma unroll
            for (int fm = 0; fm < 2; ++fm) {
                float s = 0.f;
                if (k < 225) {
                    float a0 = ps[0 * PMSZ + pbase[fm] + o0];
                    float a1 = ps[1 * PMSZ + pbase[fm] + o1];
                    float a2 = ps[2 * PMSZ + pbase[fm] + o2];
                    float a3 = ps[3 * PMSZ + pbase[fm] + o3];
                    s = (a0 + a1) + (a2 + a3);
                }
                ua[fm][j] = f2bf(s);
            }
        }
        short8v a0v = *(short8v*)ua[0];
        short8v a1v = *(short8v*)ua[1];

        short8v bv[4];
        #pragma unroll
        for (int fn = 0; fn < 4; ++fn) {
            int e = wn * 64 + fn * 16 + lr;
            const float* ib = imgb + (size_t)e * 225;
            ushort u[8];
            #pragma unroll
            for (int j = 0; j < 8; ++j) {
                int k = ks * 32 + lk + j;
                u[j] = (k < 225) ? f2bf(ib[k]) : (ushort)0;
            }
            bv[fn] = *(short8v*)u;
        }

        acc[0][0] = __builtin_amdgcn_mfma_f32_16x16x32_bf16(a0v, bv[0], acc[0][0], 0, 0, 0);
        acc[0][1] = __builtin_amdgcn_mfma_f32_16x16x32_bf16(a0v, bv[1], acc[0][1], 0, 0, 0);
        acc[0][2] = __builtin_amdgcn_mfma_f32_16x16x32_bf16(a0v, bv[2], acc[0][2], 0, 0, 0);
        acc[0][3] = __builtin_amdgcn_mfma_f32_16x16x32_bf16(a0v, bv[3], acc[0][3], 0, 0, 0);
        acc[1][0] = __builtin_amdgcn_mfma_f32_16x16x32_bf16(a1v, bv[0], acc[1][0], 0, 0, 0);
        acc[1][1] = __builtin_amdgcn_mfma_f32_16x16x32_bf16(a1v, bv[1], acc[1][1], 0, 0, 0);
        acc[1][2] = __builtin_amdgcn_mfma_f32_16x16x32_bf16(a1v, bv[2], acc[1][2], 0, 0, 0);
        acc[1][3] = __builtin_amdgcn_mfma_f32_16x16x32_bf16(a1v, bv[3], acc[1][3], 0, 0, 0);
    }

    #pragma unroll
    for (int fm = 0; fm < 2; ++fm) {
        #pragma unroll
        for (int r4 = 0; r4 < 4; ++r4) {
            int p = p0 + wm * 32 + fm * 16 + (lane >> 4) * 4 + r4;
            if (p < PP) {
                ushort* dst = reg16 + ((size_t)b * PP + p) * EE;
                #pragma unroll
                for (int fn = 0; fn < 4; ++fn) {
                    int e = wn * 64 + fn * 16 + (lane & 15);
                    dst[e] = f2bf(acc[fm][fn][r4]);
                }
            }
        }
    }
}

// LSTM v2 (R16-proven): 128n x 128jp block, 4 waves (2x2), 4x4 frags of
// 16x16x32 MFMA; epilogue in two jp-halves; fused transposed maps write.
__global__ __launch_bounds__(256) void k_lstm(const ushort* __restrict__ reg16,
                                              const ushort* __restrict__ hb16in,
                                              const ushort* __restrict__ Wt,
                                              const float* __restrict__ bc,
                                              ushort* __restrict__ hb16out,
                                              float* __restrict__ cst,
                                              float* __restrict__ out, int t) {
    __shared__ float gsm[128][68];
    __shared__ float h2sm[128][17];
    const int tid = threadIdx.x;
    const int wave = tid >> 6, lane = tid & 63;
    const int wm = wave >> 1, wn = wave & 1;
    const int n0 = blockIdx.x * 128;
    const int jp0 = blockIdx.y * 128;
    const int lr = lane & 15;
    const int lk = (lane >> 4) * 8;

    f32x4 acc[4][4];
    #pragma unroll
    for (int fm = 0; fm < 4; ++fm)
        #pragma unroll
        for (int fn = 0; fn < 4; ++fn) acc[fm][fn] = (f32x4){0.f, 0.f, 0.f, 0.f};

    size_t aoff[4];
    #pragma unroll
    for (int fm = 0; fm < 4; ++fm) {
        int n = n0 + wm * 64 + fm * 16 + lr;
        aoff[fm] = (size_t)((n < NROWS) ? n : (NROWS - 1)) * EE;
    }
    size_t boff[4];
    #pragma unroll
    for (int fn = 0; fn < 4; ++fn)
        boff[fn] = (size_t)(jp0 + wn * 64 + fn * 16 + lr) * 256;

    for (int ks = 0; ks < 8; ++ks) {     // not unrolled (VGPR guard)
        const ushort* src = (ks < 4) ? reg16 : hb16in;
        const int koff = ((ks < 4) ? ks : (ks - 4)) * 32 + lk;
        short8v a[4], bv[4];
        #pragma unroll
        for (int fm = 0; fm < 4; ++fm) a[fm] = *(const short8v*)(src + aoff[fm] + koff);
        #pragma unroll
        for (int fn = 0; fn < 4; ++fn) bv[fn] = *(const short8v*)(Wt + boff[fn] + ks * 32 + lk);
        #pragma unroll
        for (int fm = 0; fm < 4; ++fm)
            #pragma unroll
            for (int fn = 0; fn < 4; ++fn)
                acc[fm][fn] = __builtin_amdgcn_mfma_f32_16x16x32_bf16(a[fm], bv[fn], acc[fm][fn], 0, 0, 0);
    }

    #pragma unroll
    for (int half = 0; half < 2; ++half) {
        if (wn == half) {
            #pragma unroll
            for (int fm = 0; fm < 4; ++fm)
                #pragma unroll
                for (int fn = 0; fn < 4; ++fn)
                    #pragma unroll
                    for (int r = 0; r < 4; ++r)
                        gsm[wm * 64 + fm * 16 + (lane >> 4) * 4 + r]
                           [fn * 16 + (lane & 15)] = acc[fm][fn][r];
        }
        __syncthreads();

        const int jph0 = jp0 + half * 64;
        const int jjl = tid & 15;
        const int jj = (jph0 >> 2) + jjl;
        const float4 bvv = *(const float4*)(bc + jph0 + jjl * 4);
        for (int i = 0; i < 8; ++i) {
            int nrel = (tid >> 4) * 8 + i;
            int n = n0 + nrel;
            float4 g = *(const float4*)&gsm[nrel][jjl * 4];
            float h2 = 0.f;
            if (n < NROWS) {
                float gi = g.x + bvv.x, gf = g.y + bvv.y, gg = g.z + bvv.z, go = g.w + bvv.w;
                size_t off = (size_t)n * EE + jj;
                float cv = cst[off];
                float c2 = sigf(gf) * cv + sigf(gi) * tanhf(gg);
                h2 = sigf(go) * tanhf(c2);
                cst[off] = c2;
                hb16out[off] = f2bf(h2);
            }
            h2sm[nrel][jjl] = h2;
        }
        __syncthreads();

        const int nrel2 = tid & 127;
        const int n2 = n0 + nrel2;
        if (n2 < NROWS) {
            const int b2 = n2 / PP, p2 = n2 - b2 * PP;
            const size_t base = MAPS_OFF + ((size_t)(b2 * NSTEP + t) * EE) * PP + p2;
            #pragma unroll
            for (int pass = 0; pass < 8; ++pass) {
                int jl = pass * 2 + (tid >> 7);
                out[base + (size_t)((jph0 >> 2) + jl) * PP] = h2sm[nrel2][jl];
            }
        }
        __syncthreads();
    }
}

// wprep: wT16[b][o][tap][e] = bf16( rot_o(img[b,t+1])[e][tap] )
// XCD-swizzled: 1D grid 128 = 8 xcd x 16 slots; each XCD owns 2 b's so the
// per-b img read (230 KB) stays in that XCD's L2.
__global__ __launch_bounds__(256) void k_wprep(const float* __restrict__ images,
                                               ushort* __restrict__ wT16, int t) {
    __shared__ float img_s[64][225];
    const int lin  = blockIdx.x;
    const int xcd  = lin & 7;
    const int slot = lin >> 3;            // 0..15
    const int b  = xcd * 2 + (slot >> 3); // 8 slots per b
    const int rem = slot & 7;
    const int eh = rem & 1;
    const int o  = rem >> 1;
    const int tid = threadIdx.x;
    const float* img = images + ((size_t)(b * TT + t + 1) * EE + eh * 64) * 225;
    for (int i = tid; i < 64 * 225; i += 256)
        img_s[i / 225][i % 225] = img[i];
    __syncthreads();
    ushort* w = wT16 + ((size_t)(b * OO + o) * 225) * EE + eh * 64;
    for (int j = tid; j < 225 * 64; j += 256) {
        int tap = j >> 6, el = j & 63;
        int r = tap / 15, c = tap - r * 15;
        w[(size_t)tap * EE + el] = f2bf(img_s[el][rotoff(o, r, c)]);
    }
}

// localize v9 + XCD swizzle: 1D grid 1296 = 8 xcd x 162 slots; each XCD owns
// 2 b's (81 blocks each) so wT16[b] (460 KB) and h16[b] (430 KB) are read
// into ONE XCD's L2 instead of all 8 (kills the ~8x L2-fill amplification).
// Inner kernel identical to R15/R16-proven v9.
__global__ __launch_bounds__(256) void k_localize(const ushort* __restrict__ h16,
                                                  const ushort* __restrict__ wT16,
                                                  float* __restrict__ rawp) {
    __shared__ ushort tile[5 * MM * EE];   // 52,480 B
    const int lin  = blockIdx.x;
    const int xcd  = lin & 7;
    const int slot = lin >> 3;             // 0..161
    const int b    = xcd * 2 + (slot / 81);
    const int rem  = slot % 81;
    const int y    = rem % SS;
    const int dyt  = rem / SS;             // 0..2
    const int tid = threadIdx.x;
    const int o    = tid >> 6;             // wave = orientation
    const int lane = tid & 63;             // e-pair index
    const int dy0 = dyt * 5;

    const uint4* s4 = (const uint4*)(h16 + ((size_t)b * PP + (size_t)(y + dy0) * MM) * EE);
    uint4* d4 = (uint4*)tile;
    for (int i = tid; i < 3280; i += 256) d4[i] = s4[i];
    __syncthreads();

    float acc[SS];
    #pragma unroll
    for (int x = 0; x < SS; ++x) acc[x] = 0.f;

    const uint* tl = (const uint*)tile + lane;
    const uint* wo = (const uint*)(wT16 + (((size_t)b * OO + o) * 225) * EE) + lane;

    for (int dyl = 0; dyl < 5; ++dyl) {    // NOT unrolled (spill guard)
        uint hrow[MM];
        const uint* tr = tl + (size_t)dyl * MM * 64;
        #pragma unroll
        for (int c = 0; c < MM; ++c) hrow[c] = tr[c * 64];
        const uint* wd = wo + (size_t)((dy0 + dyl) * 15) * 64;
        #pragma unroll
        for (int dx = 0; dx < 15; ++dx) {
            uint uw = wd[dx * 64];
#if __has_builtin(__builtin_amdgcn_fdot2_f32_bf16)
            bf16x2 w2 = __builtin_bit_cast(bf16x2, uw);
            #pragma unroll
            for (int x = 0; x < SS; ++x)
                acc[x] = __builtin_amdgcn_fdot2_f32_bf16(
                    __builtin_bit_cast(bf16x2, hrow[x + dx]), w2, acc[x], false);
#else
            float wl = bf2f((ushort)(uw & 0xffffu));
            float wh = bf2f((ushort)(uw >> 16));
            #pragma unroll
            for (int x = 0; x < SS; ++x) {
                uint hu = hrow[x + dx];
                acc[x] += bf2f((ushort)(hu & 0xffffu)) * wl
                        + bf2f((ushort)(hu >> 16)) * wh;
            }
#endif
        }
    }

    #pragma unroll
    for (int x = 0; x < SS; ++x) {
        float v = acc[x];
        v += __shfl_xor(v, 1);  v += __shfl_xor(v, 2);  v += __shfl_xor(v, 4);
        v += __shfl_xor(v, 8);  v += __shfl_xor(v, 16); v += __shfl_xor(v, 32);
        if (lane == 0)
            rawp[(((size_t)dyt * BB + b) * OO + o) * (SS * SS) + y * SS + x] = v;
    }
}

__global__ __launch_bounds__(256) void k_softmax(const float* __restrict__ rawp,
                                                 float* __restrict__ out,
                                                 float* __restrict__ pose, int t) {
    const int b = blockIdx.x, tid = threadIdx.x;
    const int NTOT = OO * SS * SS;
    __shared__ float sv[OO * SS * SS];
    __shared__ float red[256];

    const float* p0 = rawp + (size_t)b * NTOT;
    for (int i = tid; i < NTOT; i += 256) {
        float s = 0.f;
        #pragma unroll
        for (int q = 0; q < NPS; ++q) s += p0[(size_t)q * BB * NTOT + i];
        sv[i] = s;
    }
    __syncthreads();

    float mx = -3.4e38f;
    for (int i = tid; i < NTOT; i += 256) mx = fmaxf(mx, sv[i]);
    red[tid] = mx; __syncthreads();
    for (int s = 128; s > 0; s >>= 1) {
        if (tid < s) red[tid] = fmaxf(red[tid], red[tid + s]);
        __syncthreads();
    }
    mx = red[0]; __syncthreads();

    float sm = 0.f;
    for (int i = tid; i < NTOT; i += 256) sm += expf(sv[i] - mx);
    red[tid] = sm; __syncthreads();
    for (int s = 128; s > 0; s >>= 1) {
        if (tid < s) red[tid] += red[tid + s];
        __syncthreads();
    }
    const float inv = 1.f / red[0];

    float* rawOut = out + RAWS_OFF + ((size_t)(b * NSTEP + t) * OO) * PP;
    float* spOut  = out + SPS_OFF  + ((size_t)(b * NSTEP + t) * OO) * PP;
    float* pb = pose + (size_t)b * OO * MM * MM;
    for (int i = tid; i < OO * MM * MM; i += 256) {
        int o = i / (MM * MM), rem = i % (MM * MM), yy = rem / MM - VR, xx = rem % MM - VR;
        float rv = 0.f, sv2 = 0.f;
        if ((unsigned)yy < SS && (unsigned)xx < SS) {
            float r = sv[(o * SS + yy) * SS + xx];
            rv = r;
            sv2 = expf(r - mx) * inv;
        }
        rawOut[i] = rv;
        spOut[i] = sv2;
        pb[i] = sv2;
    }
}

extern "C" void kernel_launch(void* const* d_in, const int* in_sizes, int n_in,
                              void* d_out, int out_size, void* d_ws, size_t ws_size,
                              hipStream_t stream) {
    const float* images = (const float*)d_in[0];
    const float* wih    = (const float*)d_in[1];
    const float* whh    = (const float*)d_in[2];
    const float* bih    = (const float*)d_in[3];
    const float* bhh    = (const float*)d_in[4];
    float* out = (float*)d_out;
    float* ws  = (float*)d_ws;

    // layout (float units), total ~10.5M floats = 42 MB
    float*  pose  = ws;                                   // 107,584
    float*  cst   = pose + 107584;                        // 3,442,688 fp32
    ushort* hbA   = (ushort*)(cst + 3442688);             // 1,721,344 float-slots
    ushort* hbB   = (ushort*)(cst + 3442688 + 1721344);   // 1,721,344 float-slots
    float*  regbF = cst + 3442688 + 2 * 1721344;          // 3,442,688 region
    ushort* reg16 = (ushort*)regbF;                       // bf16 reg
    // aliases inside regb region (dead between k_lstm(t) and k_register(t+1)):
    float*  rawp  = regbF;                                // 139,968 floats (NPS=3)
    ushort* wT16  = (ushort*)(regbF + 262144);            // 921,600 float-slots
    ushort* Wt    = (ushort*)(regbF + 3442688);           // 65,536 float-slots
    float*  bc    = regbF + 3442688 + 65536;              // 512

    hipMemsetAsync(hbA, 0, (size_t)1721344 * 4, stream);
    hipMemsetAsync(cst, 0, (size_t)3442688 * 4, stream);
    k_init<<<421, 256, 0, stream>>>(pose);
    k_prep<<<512, 256, 0, stream>>>(wih, whh, bih, bhh, Wt, bc);

    ushort* hbin = hbA;
    ushort* hbout = hbB;
    for (int t = 0; t < NSTEP; ++t) {
        k_register<<<dim3(27, BB), 256, 0, stream>>>(images, pose, reg16, t);
        k_lstm<<<dim3(211, 4), 256, 0, stream>>>(reg16, hbin, Wt, bc, hbout, cst, out, t);
        k_wprep<<<128, 256, 0, stream>>>(images, wT16, t);
        k_localize<<<1296, 256, 0, stream>>>(hbout, wT16, rawp);
        k_softmax<<<BB, 256, 0, stream>>>(rawp, out, pose, t);
        ushort* tmp = hbin; hbin = hbout; hbout = tmp;
    }
}

// Round 23
// 1964.114 us; speedup vs baseline: 1.9758x; 1.1004x over previous
//
#include <hip/hip_runtime.h>
#include <math.h>

#define BB 16
#define TT 16
#define EE 128
#define KS 15
#define MM 41
#define OO 4
#define VR 7
#define SS 27
#define NSTEP 15
#define PP (MM*MM)
#define NROWS (BB*PP)

#define RAWS_OFF 0
#define SPS_OFF  1613760
#define MAPS_OFF 3227520

#define PM 55
#define PMSZ (PM*PM)
#define NPS 3

typedef __attribute__((ext_vector_type(8))) short short8v;
typedef __attribute__((ext_vector_type(4))) float f32x4;
typedef __attribute__((ext_vector_type(2))) __bf16 bf16x2;
typedef unsigned short ushort;
typedef unsigned int uint;

__device__ __forceinline__ float sigf(float x) { return 1.f / (1.f + expf(-x)); }

__device__ __forceinline__ ushort f2bf(float x) {
    unsigned int u = __float_as_uint(x);
    u += 0x7FFF + ((u >> 16) & 1);
    return (ushort)(u >> 16);
}
__device__ __forceinline__ float bf2f(ushort u) {
    return __uint_as_float((unsigned int)u << 16);
}

__device__ __forceinline__ int rotoff(int o, int r, int c) {
    int ir, ic;
    if (o == 0)      { ir = r;      ic = c;      }
    else if (o == 1) { ir = c;      ic = 14 - r; }
    else if (o == 2) { ir = 14 - r; ic = 14 - c; }
    else             { ir = 14 - c; ic = r;      }
    return ir * 15 + ic;
}

__global__ void k_init(float* __restrict__ pose) {
    int idx = blockIdx.x * 256 + threadIdx.x;
    if (idx < BB * OO * MM * MM) {
        int r = idx % (OO * MM * MM);
        pose[idx] = (r == (20 * MM + 20)) ? 1.f : 0.f;
    }
}

// Wt[jp][k] bf16 (B^T layout for MFMA), jp = jj*4+g; bc[jp] = bih+bhh
__global__ void k_prep(const float* __restrict__ wih, const float* __restrict__ whh,
                       const float* __restrict__ bih, const float* __restrict__ bhh,
                       ushort* __restrict__ Wt, float* __restrict__ bc) {
    int idx = blockIdx.x * 256 + threadIdx.x;   // [0, 512*256)
    int jp = idx >> 8, k = idx & 255;
    int jj = jp >> 2, g = jp & 3, j = g * 128 + jj;
    float v = (k < 128) ? wih[j * 128 + k] : whh[j * 128 + (k - 128)];
    Wt[(size_t)jp * 256 + k] = f2bf(v);
    if (idx < 512) {
        int jj2 = idx >> 2, g2 = idx & 3, j2 = g2 * 128 + jj2;
        bc[idx] = bih[j2] + bhh[j2];
    }
}

// FUSED register+wprep: blocks 0..431 = register v4 (R21-proven, unchanged
// math); blocks 432..559 = wprep (img staged bf16, 28.8 KB, fits in the
// 48.4 KB union buffer). The two are data-independent (both read only
// images/pose); wT16 moved OUT of the reg16 alias region to make this legal.
// One dispatch instead of two; wprep rides register's idle CU slots.
__global__ __launch_bounds__(256) void k_regwprep(const float* __restrict__ images,
                                                  const float* __restrict__ pose,
                                                  ushort* __restrict__ reg16,
                                                  ushort* __restrict__ wT16, int t) {
    __shared__ float smem[OO * PMSZ];    // 48.4 KB union
    const int tid = threadIdx.x;

    if (blockIdx.x < 432) {
        // ---------------- register path ----------------
        float* ps = smem;
        const int bx = blockIdx.x;
        const int p0 = (bx % 27) * 64;
        const int b  = bx / 27;

        for (int i = tid; i < OO * PMSZ; i += 256) {
            int o = i / PMSZ, rem = i % PMSZ, r = rem / PM, c = rem % PM;
            float v = 0.f;
            if (r >= VR && r < VR + MM && c >= VR && c < VR + MM)
                v = pose[(((size_t)b * OO + o) * MM + (r - VR)) * MM + (c - VR)];
            ps[i] = v;
        }
        __syncthreads();

        const int wave = tid >> 6, lane = tid & 63;
        const int wm = wave >> 1, wn = wave & 1;
        const int lr = lane & 15;
        const int lk = (lane >> 4) * 8;

        int pbase[2];
        #pragma unroll
        for (int fm = 0; fm < 2; ++fm) {
            int p = p0 + wm * 32 + fm * 16 + lr;
            int pc = (p < PP) ? p : 0;
            int y = pc / MM, x = pc - y * MM;
            pbase[fm] = (y + 2 * VR) * PM + (x + 2 * VR);
        }
        const float* imgb = images + ((size_t)(b * TT + t) * EE) * 225;

        f32x4 acc[2][4];
        #pragma unroll
        for (int fm = 0; fm < 2; ++fm)
            #pragma unroll
            for (int fn = 0; fn < 4; ++fn) acc[fm][fn] = (f32x4){0.f, 0.f, 0.f, 0.f};

        for (int ks = 0; ks < 8; ++ks) {     // not unrolled (VGPR guard)
            ushort ua[2][8];
            #pragma unroll
            for (int j = 0; j < 8; ++j) {
                int k = ks * 32 + lk + j;
                int kk = (k < 225) ? k : 0;
                int R = kk / 15, C = kk - R * 15;
                int o0 = -R * PM - C;
                int o1 = (C - 14) * PM - R;
                int o2 = (R - 14) * PM + (C - 14);
                int o3 = -C * PM + (R - 14);
                #pragma unroll
                for (int fm = 0; fm < 2; ++fm) {
                    float s = 0.f;
                    if (k < 225) {
                        float a0 = ps[0 * PMSZ + pbase[fm] + o0];
                        float a1 = ps[1 * PMSZ + pbase[fm] + o1];
                        float a2 = ps[2 * PMSZ + pbase[fm] + o2];
                        float a3 = ps[3 * PMSZ + pbase[fm] + o3];
                        s = (a0 + a1) + (a2 + a3);
                    }
                    ua[fm][j] = f2bf(s);
                }
            }
            short8v a0v = *(short8v*)ua[0];
            short8v a1v = *(short8v*)ua[1];

            short8v bv[4];
            #pragma unroll
            for (int fn = 0; fn < 4; ++fn) {
                int e = wn * 64 + fn * 16 + lr;
                const float* ib = imgb + (size_t)e * 225;
                ushort u[8];
                #pragma unroll
                for (int j = 0; j < 8; ++j) {
                    int k = ks * 32 + lk + j;
                    u[j] = (k < 225) ? f2bf(ib[k]) : (ushort)0;
                }
                bv[fn] = *(short8v*)u;
            }

            acc[0][0] = __builtin_amdgcn_mfma_f32_16x16x32_bf16(a0v, bv[0], acc[0][0], 0, 0, 0);
            acc[0][1] = __builtin_amdgcn_mfma_f32_16x16x32_bf16(a0v, bv[1], acc[0][1], 0, 0, 0);
            acc[0][2] = __builtin_amdgcn_mfma_f32_16x16x32_bf16(a0v, bv[2], acc[0][2], 0, 0, 0);
            acc[0][3] = __builtin_amdgcn_mfma_f32_16x16x32_bf16(a0v, bv[3], acc[0][3], 0, 0, 0);
            acc[1][0] = __builtin_amdgcn_mfma_f32_16x16x32_bf16(a1v, bv[0], acc[1][0], 0, 0, 0);
            acc[1][1] = __builtin_amdgcn_mfma_f32_16x16x32_bf16(a1v, bv[1], acc[1][1], 0, 0, 0);
            acc[1][2] = __builtin_amdgcn_mfma_f32_16x16x32_bf16(a1v, bv[2], acc[1][2], 0, 0, 0);
            acc[1][3] = __builtin_amdgcn_mfma_f32_16x16x32_bf16(a1v, bv[3], acc[1][3], 0, 0, 0);
        }

        #pragma unroll
        for (int fm = 0; fm < 2; ++fm) {
            #pragma unroll
            for (int r4 = 0; r4 < 4; ++r4) {
                int p = p0 + wm * 32 + fm * 16 + (lane >> 4) * 4 + r4;
                if (p < PP) {
                    ushort* dst = reg16 + ((size_t)b * PP + p) * EE;
                    #pragma unroll
                    for (int fn = 0; fn < 4; ++fn) {
                        int e = wn * 64 + fn * 16 + (lane & 15);
                        dst[e] = f2bf(acc[fm][fn][r4]);
                    }
                }
            }
        }
    } else {
        // ---------------- wprep path (XCD-swizzled decode kept) ----------------
        ushort* img_s = (ushort*)smem;    // [64][225] bf16 = 28.8 KB
        const int lin  = blockIdx.x - 432;
        const int xcd  = lin & 7;
        const int slot = lin >> 3;            // 0..15
        const int b  = xcd * 2 + (slot >> 3);
        const int rem = slot & 7;
        const int eh = rem & 1;
        const int o  = rem >> 1;
        const float* img = images + ((size_t)(b * TT + t + 1) * EE + eh * 64) * 225;
        for (int i = tid; i < 64 * 225; i += 256)
            img_s[i] = f2bf(img[i]);          // [el][tap] layout, coalesced
        __syncthreads();
        ushort* w = wT16 + ((size_t)(b * OO + o) * 225) * EE + eh * 64;
        for (int j = tid; j < 225 * 64; j += 256) {
            int tap = j >> 6, el = j & 63;
            int r = tap / 15, c = tap - r * 15;
            w[(size_t)tap * EE + el] = img_s[el * 225 + rotoff(o, r, c)];
        }
    }
}

// LSTM v2 (R16-proven): 128n x 128jp block, 4 waves (2x2), 4x4 frags of
// 16x16x32 MFMA; epilogue in two jp-halves; fused transposed maps write.
__global__ __launch_bounds__(256) void k_lstm(const ushort* __restrict__ reg16,
                                              const ushort* __restrict__ hb16in,
                                              const ushort* __restrict__ Wt,
                                              const float* __restrict__ bc,
                                              ushort* __restrict__ hb16out,
                                              float* __restrict__ cst,
                                              float* __restrict__ out, int t) {
    __shared__ float gsm[128][68];
    __shared__ float h2sm[128][17];
    const int tid = threadIdx.x;
    const int wave = tid >> 6, lane = tid & 63;
    const int wm = wave >> 1, wn = wave & 1;
    const int n0 = blockIdx.x * 128;
    const int jp0 = blockIdx.y * 128;
    const int lr = lane & 15;
    const int lk = (lane >> 4) * 8;

    f32x4 acc[4][4];
    #pragma unroll
    for (int fm = 0; fm < 4; ++fm)
        #pragma unroll
        for (int fn = 0; fn < 4; ++fn) acc[fm][fn] = (f32x4){0.f, 0.f, 0.f, 0.f};

    size_t aoff[4];
    #pragma unroll
    for (int fm = 0; fm < 4; ++fm) {
        int n = n0 + wm * 64 + fm * 16 + lr;
        aoff[fm] = (size_t)((n < NROWS) ? n : (NROWS - 1)) * EE;
    }
    size_t boff[4];
    #pragma unroll
    for (int fn = 0; fn < 4; ++fn)
        boff[fn] = (size_t)(jp0 + wn * 64 + fn * 16 + lr) * 256;

    for (int ks = 0; ks < 8; ++ks) {     // not unrolled (VGPR guard)
        const ushort* src = (ks < 4) ? reg16 : hb16in;
        const int koff = ((ks < 4) ? ks : (ks - 4)) * 32 + lk;
        short8v a[4], bv[4];
        #pragma unroll
        for (int fm = 0; fm < 4; ++fm) a[fm] = *(const short8v*)(src + aoff[fm] + koff);
        #pragma unroll
        for (int fn = 0; fn < 4; ++fn) bv[fn] = *(const short8v*)(Wt + boff[fn] + ks * 32 + lk);
        #pragma unroll
        for (int fm = 0; fm < 4; ++fm)
            #pragma unroll
            for (int fn = 0; fn < 4; ++fn)
                acc[fm][fn] = __builtin_amdgcn_mfma_f32_16x16x32_bf16(a[fm], bv[fn], acc[fm][fn], 0, 0, 0);
    }

    #pragma unroll
    for (int half = 0; half < 2; ++half) {
        if (wn == half) {
            #pragma unroll
            for (int fm = 0; fm < 4; ++fm)
                #pragma unroll
                for (int fn = 0; fn < 4; ++fn)
                    #pragma unroll
                    for (int r = 0; r < 4; ++r)
                        gsm[wm * 64 + fm * 16 + (lane >> 4) * 4 + r]
                           [fn * 16 + (lane & 15)] = acc[fm][fn][r];
        }
        __syncthreads();

        const int jph0 = jp0 + half * 64;
        const int jjl = tid & 15;
        const int jj = (jph0 >> 2) + jjl;
        const float4 bvv = *(const float4*)(bc + jph0 + jjl * 4);
        for (int i = 0; i < 8; ++i) {
            int nrel = (tid >> 4) * 8 + i;
            int n = n0 + nrel;
            float4 g = *(const float4*)&gsm[nrel][jjl * 4];
            float h2 = 0.f;
            if (n < NROWS) {
                float gi = g.x + bvv.x, gf = g.y + bvv.y, gg = g.z + bvv.z, go = g.w + bvv.w;
                size_t off = (size_t)n * EE + jj;
                float cv = cst[off];
                float c2 = sigf(gf) * cv + sigf(gi) * tanhf(gg);
                h2 = sigf(go) * tanhf(c2);
                cst[off] = c2;
                hb16out[off] = f2bf(h2);
            }
            h2sm[nrel][jjl] = h2;
        }
        __syncthreads();

        const int nrel2 = tid & 127;
        const int n2 = n0 + nrel2;
        if (n2 < NROWS) {
            const int b2 = n2 / PP, p2 = n2 - b2 * PP;
            const size_t base = MAPS_OFF + ((size_t)(b2 * NSTEP + t) * EE) * PP + p2;
            #pragma unroll
            for (int pass = 0; pass < 8; ++pass) {
                int jl = pass * 2 + (tid >> 7);
                out[base + (size_t)((jph0 >> 2) + jl) * PP] = h2sm[nrel2][jl];
            }
        }
        __syncthreads();
    }
}

// localize v9 + XCD swizzle (R22-proven): 1D grid 1296 = 8 xcd x 162 slots.
__global__ __launch_bounds__(256) void k_localize(const ushort* __restrict__ h16,
                                                  const ushort* __restrict__ wT16,
                                                  float* __restrict__ rawp) {
    __shared__ ushort tile[5 * MM * EE];   // 52,480 B
    const int lin  = blockIdx.x;
    const int xcd  = lin & 7;
    const int slot = lin >> 3;             // 0..161
    const int b    = xcd * 2 + (slot / 81);
    const int rem  = slot % 81;
    const int y    = rem % SS;
    const int dyt  = rem / SS;             // 0..2
    const int tid = threadIdx.x;
    const int o    = tid >> 6;             // wave = orientation
    const int lane = tid & 63;             // e-pair index
    const int dy0 = dyt * 5;

    const uint4* s4 = (const uint4*)(h16 + ((size_t)b * PP + (size_t)(y + dy0) * MM) * EE);
    uint4* d4 = (uint4*)tile;
    for (int i = tid; i < 3280; i += 256) d4[i] = s4[i];
    __syncthreads();

    float acc[SS];
    #pragma unroll
    for (int x = 0; x < SS; ++x) acc[x] = 0.f;

    const uint* tl = (const uint*)tile + lane;
    const uint* wo = (const uint*)(wT16 + (((size_t)b * OO + o) * 225) * EE) + lane;

    for (int dyl = 0; dyl < 5; ++dyl) {    // NOT unrolled (spill guard)
        uint hrow[MM];
        const uint* tr = tl + (size_t)dyl * MM * 64;
        #pragma unroll
        for (int c = 0; c < MM; ++c) hrow[c] = tr[c * 64];
        const uint* wd = wo + (size_t)((dy0 + dyl) * 15) * 64;
        #pragma unroll
        for (int dx = 0; dx < 15; ++dx) {
            uint uw = wd[dx * 64];
#if __has_builtin(__builtin_amdgcn_fdot2_f32_bf16)
            bf16x2 w2 = __builtin_bit_cast(bf16x2, uw);
            #pragma unroll
            for (int x = 0; x < SS; ++x)
                acc[x] = __builtin_amdgcn_fdot2_f32_bf16(
                    __builtin_bit_cast(bf16x2, hrow[x + dx]), w2, acc[x], false);
#else
            float wl = bf2f((ushort)(uw & 0xffffu));
            float wh = bf2f((ushort)(uw >> 16));
            #pragma unroll
            for (int x = 0; x < SS; ++x) {
                uint hu = hrow[x + dx];
                acc[x] += bf2f((ushort)(hu & 0xffffu)) * wl
                        + bf2f((ushort)(hu >> 16)) * wh;
            }
#endif
        }
    }

    #pragma unroll
    for (int x = 0; x < SS; ++x) {
        float v = acc[x];
        v += __shfl_xor(v, 1);  v += __shfl_xor(v, 2);  v += __shfl_xor(v, 4);
        v += __shfl_xor(v, 8);  v += __shfl_xor(v, 16); v += __shfl_xor(v, 32);
        if (lane == 0)
            rawp[(((size_t)dyt * BB + b) * OO + o) * (SS * SS) + y * SS + x] = v;
    }
}

__global__ __launch_bounds__(256) void k_softmax(const float* __restrict__ rawp,
                                                 float* __restrict__ out,
                                                 float* __restrict__ pose, int t) {
    const int b = blockIdx.x, tid = threadIdx.x;
    const int NTOT = OO * SS * SS;
    __shared__ float sv[OO * SS * SS];
    __shared__ float red[256];

    const float* p0 = rawp + (size_t)b * NTOT;
    for (int i = tid; i < NTOT; i += 256) {
        float s = 0.f;
        #pragma unroll
        for (int q = 0; q < NPS; ++q) s += p0[(size_t)q * BB * NTOT + i];
        sv[i] = s;
    }
    __syncthreads();

    float mx = -3.4e38f;
    for (int i = tid; i < NTOT; i += 256) mx = fmaxf(mx, sv[i]);
    red[tid] = mx; __syncthreads();
    for (int s = 128; s > 0; s >>= 1) {
        if (tid < s) red[tid] = fmaxf(red[tid], red[tid + s]);
        __syncthreads();
    }
    mx = red[0]; __syncthreads();

    float sm = 0.f;
    for (int i = tid; i < NTOT; i += 256) sm += expf(sv[i] - mx);
    red[tid] = sm; __syncthreads();
    for (int s = 128; s > 0; s >>= 1) {
        if (tid < s) red[tid] += red[tid + s];
        __syncthreads();
    }
    const float inv = 1.f / red[0];

    float* rawOut = out + RAWS_OFF + ((size_t)(b * NSTEP + t) * OO) * PP;
    float* spOut  = out + SPS_OFF  + ((size_t)(b * NSTEP + t) * OO) * PP;
    float* pb = pose + (size_t)b * OO * MM * MM;
    for (int i = tid; i < OO * MM * MM; i += 256) {
        int o = i / (MM * MM), rem = i % (MM * MM), yy = rem / MM - VR, xx = rem % MM - VR;
        float rv = 0.f, sv2 = 0.f;
        if ((unsigned)yy < SS && (unsigned)xx < SS) {
            float r = sv[(o * SS + yy) * SS + xx];
            rv = r;
            sv2 = expf(r - mx) * inv;
        }
        rawOut[i] = rv;
        spOut[i] = sv2;
        pb[i] = sv2;
    }
}

extern "C" void kernel_launch(void* const* d_in, const int* in_sizes, int n_in,
                              void* d_out, int out_size, void* d_ws, size_t ws_size,
                              hipStream_t stream) {
    const float* images = (const float*)d_in[0];
    const float* wih    = (const float*)d_in[1];
    const float* whh    = (const float*)d_in[2];
    const float* bih    = (const float*)d_in[3];
    const float* bhh    = (const float*)d_in[4];
    float* out = (float*)d_out;
    float* ws  = (float*)d_ws;

    // layout (float units), total ~11.42M floats = 45.7 MB (wT16 de-aliased
    // so the fused regwprep kernel can write it before k_lstm reads reg16)
    float*  pose  = ws;                                   // 107,584
    float*  cst   = pose + 107584;                        // 3,442,688 fp32
    ushort* hbA   = (ushort*)(cst + 3442688);             // 1,721,344 float-slots
    ushort* hbB   = (ushort*)(cst + 3442688 + 1721344);   // 1,721,344 float-slots
    float*  regbF = cst + 3442688 + 2 * 1721344;          // 3,442,688 region
    ushort* reg16 = (ushort*)regbF;                       // bf16 reg
    float*  rawp  = regbF;                                // alias (post-lstm), 139,968 fl
    ushort* wT16  = (ushort*)(regbF + 3442688);           // 921,600 float-slots (own region)
    ushort* Wt    = (ushort*)(regbF + 3442688 + 921600);  // 65,536 float-slots
    float*  bc    = regbF + 3442688 + 921600 + 65536;     // 512

    hipMemsetAsync(hbA, 0, (size_t)1721344 * 4, stream);
    hipMemsetAsync(cst, 0, (size_t)3442688 * 4, stream);
    k_init<<<421, 256, 0, stream>>>(pose);
    k_prep<<<512, 256, 0, stream>>>(wih, whh, bih, bhh, Wt, bc);

    ushort* hbin = hbA;
    ushort* hbout = hbB;
    for (int t = 0; t < NSTEP; ++t) {
        k_regwprep<<<560, 256, 0, stream>>>(images, pose, reg16, wT16, t);
        k_lstm<<<dim3(211, 4), 256, 0, stream>>>(reg16, hbin, Wt, bc, hbout, cst, out, t);
        k_localize<<<1296, 256, 0, stream>>>(hbout, wT16, rawp);
        k_softmax<<<BB, 256, 0, stream>>>(rawp, out, pose, t);
        ushort* tmp = hbin; hbin = hbout; hbout = tmp;
    }
}

// Round 24
// 1962.058 us; speedup vs baseline: 1.9779x; 1.0010x over previous
//
#include <hip/hip_runtime.h>
#include <math.h>

#define BB 16
#define TT 16
#define EE 128
#define KS 15
#define MM 41
#define OO 4
#define VR 7
#define SS 27
#define NSTEP 15
#define PP (MM*MM)
#define NROWS (BB*PP)

#define RAWS_OFF 0
#define SPS_OFF  1613760
#define MAPS_OFF 3227520

#define PM 55
#define PMSZ (PM*PM)
#define NPS 5              // localize partial slots (dy-chunks of 3)

typedef __attribute__((ext_vector_type(8))) short short8v;
typedef __attribute__((ext_vector_type(4))) float f32x4;
typedef __attribute__((ext_vector_type(2))) __bf16 bf16x2;
typedef unsigned short ushort;
typedef unsigned int uint;

__device__ __forceinline__ float sigf(float x) { return 1.f / (1.f + expf(-x)); }

__device__ __forceinline__ ushort f2bf(float x) {
    unsigned int u = __float_as_uint(x);
    u += 0x7FFF + ((u >> 16) & 1);
    return (ushort)(u >> 16);
}
__device__ __forceinline__ float bf2f(ushort u) {
    return __uint_as_float((unsigned int)u << 16);
}

__device__ __forceinline__ int rotoff(int o, int r, int c) {
    int ir, ic;
    if (o == 0)      { ir = r;      ic = c;      }
    else if (o == 1) { ir = c;      ic = 14 - r; }
    else if (o == 2) { ir = 14 - r; ic = 14 - c; }
    else             { ir = 14 - c; ic = r;      }
    return ir * 15 + ic;
}

__global__ void k_init(float* __restrict__ pose) {
    int idx = blockIdx.x * 256 + threadIdx.x;
    if (idx < BB * OO * MM * MM) {
        int r = idx % (OO * MM * MM);
        pose[idx] = (r == (20 * MM + 20)) ? 1.f : 0.f;
    }
}

// Wt[jp][k] bf16 (B^T layout for MFMA), jp = jj*4+g; bc[jp] = bih+bhh
__global__ void k_prep(const float* __restrict__ wih, const float* __restrict__ whh,
                       const float* __restrict__ bih, const float* __restrict__ bhh,
                       ushort* __restrict__ Wt, float* __restrict__ bc) {
    int idx = blockIdx.x * 256 + threadIdx.x;   // [0, 512*256)
    int jp = idx >> 8, k = idx & 255;
    int jj = jp >> 2, g = jp & 3, j = g * 128 + jj;
    float v = (k < 128) ? wih[j * 128 + k] : whh[j * 128 + (k - 128)];
    Wt[(size_t)jp * 256 + k] = f2bf(v);
    if (idx < 512) {
        int jj2 = idx >> 2, g2 = idx & 3, j2 = g2 * 128 + jj2;
        bc[idx] = bih[j2] + bhh[j2];
    }
}

// FUSED register+wprep (R23-proven): blocks 0..431 = register v4 im2col MFMA;
// blocks 432..559 = wprep (img staged bf16 in the 48.4 KB union buffer).
__global__ __launch_bounds__(256) void k_regwprep(const float* __restrict__ images,
                                                  const float* __restrict__ pose,
                                                  ushort* __restrict__ reg16,
                                                  ushort* __restrict__ wT16, int t) {
    __shared__ float smem[OO * PMSZ];    // 48.4 KB union
    const int tid = threadIdx.x;

    if (blockIdx.x < 432) {
        float* ps = smem;
        const int bx = blockIdx.x;
        const int p0 = (bx % 27) * 64;
        const int b  = bx / 27;

        for (int i = tid; i < OO * PMSZ; i += 256) {
            int o = i / PMSZ, rem = i % PMSZ, r = rem / PM, c = rem % PM;
            float v = 0.f;
            if (r >= VR && r < VR + MM && c >= VR && c < VR + MM)
                v = pose[(((size_t)b * OO + o) * MM + (r - VR)) * MM + (c - VR)];
            ps[i] = v;
        }
        __syncthreads();

        const int wave = tid >> 6, lane = tid & 63;
        const int wm = wave >> 1, wn = wave & 1;
        const int lr = lane & 15;
        const int lk = (lane >> 4) * 8;

        int pbase[2];
        #pragma unroll
        for (int fm = 0; fm < 2; ++fm) {
            int p = p0 + wm * 32 + fm * 16 + lr;
            int pc = (p < PP) ? p : 0;
            int y = pc / MM, x = pc - y * MM;
            pbase[fm] = (y + 2 * VR) * PM + (x + 2 * VR);
        }
        const float* imgb = images + ((size_t)(b * TT + t) * EE) * 225;

        f32x4 acc[2][4];
        #pragma unroll
        for (int fm = 0; fm < 2; ++fm)
            #pragma unroll
            for (int fn = 0; fn < 4; ++fn) acc[fm][fn] = (f32x4){0.f, 0.f, 0.f, 0.f};

        for (int ks = 0; ks < 8; ++ks) {     // not unrolled (VGPR guard)
            ushort ua[2][8];
            #pragma unroll
            for (int j = 0; j < 8; ++j) {
                int k = ks * 32 + lk + j;
                int kk = (k < 225) ? k : 0;
                int R = kk / 15, C = kk - R * 15;
                int o0 = -R * PM - C;
                int o1 = (C - 14) * PM - R;
                int o2 = (R - 14) * PM + (C - 14);
                int o3 = -C * PM + (R - 14);
                #pragma unroll
                for (int fm = 0; fm < 2; ++fm) {
                    float s = 0.f;
                    if (k < 225) {
                        float a0 = ps[0 * PMSZ + pbase[fm] + o0];
                        float a1 = ps[1 * PMSZ + pbase[fm] + o1];
                        float a2 = ps[2 * PMSZ + pbase[fm] + o2];
                        float a3 = ps[3 * PMSZ + pbase[fm] + o3];
                        s = (a0 + a1) + (a2 + a3);
                    }
                    ua[fm][j] = f2bf(s);
                }
            }
            short8v a0v = *(short8v*)ua[0];
            short8v a1v = *(short8v*)ua[1];

            short8v bv[4];
            #pragma unroll
            for (int fn = 0; fn < 4; ++fn) {
                int e = wn * 64 + fn * 16 + lr;
                const float* ib = imgb + (size_t)e * 225;
                ushort u[8];
                #pragma unroll
                for (int j = 0; j < 8; ++j) {
                    int k = ks * 32 + lk + j;
                    u[j] = (k < 225) ? f2bf(ib[k]) : (ushort)0;
                }
                bv[fn] = *(short8v*)u;
            }

            acc[0][0] = __builtin_amdgcn_mfma_f32_16x16x32_bf16(a0v, bv[0], acc[0][0], 0, 0, 0);
            acc[0][1] = __builtin_amdgcn_mfma_f32_16x16x32_bf16(a0v, bv[1], acc[0][1], 0, 0, 0);
            acc[0][2] = __builtin_amdgcn_mfma_f32_16x16x32_bf16(a0v, bv[2], acc[0][2], 0, 0, 0);
            acc[0][3] = __builtin_amdgcn_mfma_f32_16x16x32_bf16(a0v, bv[3], acc[0][3], 0, 0, 0);
            acc[1][0] = __builtin_amdgcn_mfma_f32_16x16x32_bf16(a1v, bv[0], acc[1][0], 0, 0, 0);
            acc[1][1] = __builtin_amdgcn_mfma_f32_16x16x32_bf16(a1v, bv[1], acc[1][1], 0, 0, 0);
            acc[1][2] = __builtin_amdgcn_mfma_f32_16x16x32_bf16(a1v, bv[2], acc[1][2], 0, 0, 0);
            acc[1][3] = __builtin_amdgcn_mfma_f32_16x16x32_bf16(a1v, bv[3], acc[1][3], 0, 0, 0);
        }

        #pragma unroll
        for (int fm = 0; fm < 2; ++fm) {
            #pragma unroll
            for (int r4 = 0; r4 < 4; ++r4) {
                int p = p0 + wm * 32 + fm * 16 + (lane >> 4) * 4 + r4;
                if (p < PP) {
                    ushort* dst = reg16 + ((size_t)b * PP + p) * EE;
                    #pragma unroll
                    for (int fn = 0; fn < 4; ++fn) {
                        int e = wn * 64 + fn * 16 + (lane & 15);
                        dst[e] = f2bf(acc[fm][fn][r4]);
                    }
                }
            }
        }
    } else {
        ushort* img_s = (ushort*)smem;    // [64][225] bf16 = 28.8 KB
        const int lin  = blockIdx.x - 432;
        const int xcd  = lin & 7;
        const int slot = lin >> 3;
        const int b  = xcd * 2 + (slot >> 3);
        const int rem = slot & 7;
        const int eh = rem & 1;
        const int o  = rem >> 1;
        const float* img = images + ((size_t)(b * TT + t + 1) * EE + eh * 64) * 225;
        for (int i = tid; i < 64 * 225; i += 256)
            img_s[i] = f2bf(img[i]);
        __syncthreads();
        ushort* w = wT16 + ((size_t)(b * OO + o) * 225) * EE + eh * 64;
        for (int j = tid; j < 225 * 64; j += 256) {
            int tap = j >> 6, el = j & 63;
            int r = tap / 15, c = tap - r * 15;
            w[(size_t)tap * EE + el] = img_s[el * 225 + rotoff(o, r, c)];
        }
    }
}

// LSTM v2 (R16-proven): 128n x 128jp block, 4 waves (2x2), 4x4 frags of
// 16x16x32 MFMA; epilogue in two jp-halves; fused transposed maps write.
__global__ __launch_bounds__(256) void k_lstm(const ushort* __restrict__ reg16,
                                              const ushort* __restrict__ hb16in,
                                              const ushort* __restrict__ Wt,
                                              const float* __restrict__ bc,
                                              ushort* __restrict__ hb16out,
                                              float* __restrict__ cst,
                                              float* __restrict__ out, int t) {
    __shared__ float gsm[128][68];
    __shared__ float h2sm[128][17];
    const int tid = threadIdx.x;
    const int wave = tid >> 6, lane = tid & 63;
    const int wm = wave >> 1, wn = wave & 1;
    const int n0 = blockIdx.x * 128;
    const int jp0 = blockIdx.y * 128;
    const int lr = lane & 15;
    const int lk = (lane >> 4) * 8;

    f32x4 acc[4][4];
    #pragma unroll
    for (int fm = 0; fm < 4; ++fm)
        #pragma unroll
        for (int fn = 0; fn < 4; ++fn) acc[fm][fn] = (f32x4){0.f, 0.f, 0.f, 0.f};

    size_t aoff[4];
    #pragma unroll
    for (int fm = 0; fm < 4; ++fm) {
        int n = n0 + wm * 64 + fm * 16 + lr;
        aoff[fm] = (size_t)((n < NROWS) ? n : (NROWS - 1)) * EE;
    }
    size_t boff[4];
    #pragma unroll
    for (int fn = 0; fn < 4; ++fn)
        boff[fn] = (size_t)(jp0 + wn * 64 + fn * 16 + lr) * 256;

    for (int ks = 0; ks < 8; ++ks) {     // not unrolled (VGPR guard)
        const ushort* src = (ks < 4) ? reg16 : hb16in;
        const int koff = ((ks < 4) ? ks : (ks - 4)) * 32 + lk;
        short8v a[4], bv[4];
        #pragma unroll
        for (int fm = 0; fm < 4; ++fm) a[fm] = *(const short8v*)(src + aoff[fm] + koff);
        #pragma unroll
        for (int fn = 0; fn < 4; ++fn) bv[fn] = *(const short8v*)(Wt + boff[fn] + ks * 32 + lk);
        #pragma unroll
        for (int fm = 0; fm < 4; ++fm)
            #pragma unroll
            for (int fn = 0; fn < 4; ++fn)
                acc[fm][fn] = __builtin_amdgcn_mfma_f32_16x16x32_bf16(a[fm], bv[fn], acc[fm][fn], 0, 0, 0);
    }

    #pragma unroll
    for (int half = 0; half < 2; ++half) {
        if (wn == half) {
            #pragma unroll
            for (int fm = 0; fm < 4; ++fm)
                #pragma unroll
                for (int fn = 0; fn < 4; ++fn)
                    #pragma unroll
                    for (int r = 0; r < 4; ++r)
                        gsm[wm * 64 + fm * 16 + (lane >> 4) * 4 + r]
                           [fn * 16 + (lane & 15)] = acc[fm][fn][r];
        }
        __syncthreads();

        const int jph0 = jp0 + half * 64;
        const int jjl = tid & 15;
        const int jj = (jph0 >> 2) + jjl;
        const float4 bvv = *(const float4*)(bc + jph0 + jjl * 4);
        for (int i = 0; i < 8; ++i) {
            int nrel = (tid >> 4) * 8 + i;
            int n = n0 + nrel;
            float4 g = *(const float4*)&gsm[nrel][jjl * 4];
            float h2 = 0.f;
            if (n < NROWS) {
                float gi = g.x + bvv.x, gf = g.y + bvv.y, gg = g.z + bvv.z, go = g.w + bvv.w;
                size_t off = (size_t)n * EE + jj;
                float cv = cst[off];
                float c2 = sigf(gf) * cv + sigf(gi) * tanhf(gg);
                h2 = sigf(go) * tanhf(c2);
                cst[off] = c2;
                hb16out[off] = f2bf(h2);
            }
            h2sm[nrel][jjl] = h2;
        }
        __syncthreads();

        const int nrel2 = tid & 127;
        const int n2 = n0 + nrel2;
        if (n2 < NROWS) {
            const int b2 = n2 / PP, p2 = n2 - b2 * PP;
            const size_t base = MAPS_OFF + ((size_t)(b2 * NSTEP + t) * EE) * PP + p2;
            #pragma unroll
            for (int pass = 0; pass < 8; ++pass) {
                int jl = pass * 2 + (tid >> 7);
                out[base + (size_t)((jph0 >> 2) + jl) * PP] = h2sm[nrel2][jl];
            }
        }
        __syncthreads();
    }
}

// localize v11: dy-chunks of 3 (NPS=5) -> LDS slab 3x41x128 bf16 = 31.5 KB
// -> 5 blocks/CU (was 3). Grid 2160 = 8 xcd x 270 slots (XCD swizzle kept).
// Staged bytes unchanged (chunks disjoint); inner loop identical to v9.
__global__ __launch_bounds__(256) void k_localize(const ushort* __restrict__ h16,
                                                  const ushort* __restrict__ wT16,
                                                  float* __restrict__ rawp) {
    __shared__ ushort tile[3 * MM * EE];   // 31,488 B
    const int lin  = blockIdx.x;
    const int xcd  = lin & 7;
    const int slot = lin >> 3;             // 0..269
    const int b    = xcd * 2 + (slot / 135);
    const int rem  = slot % 135;
    const int y    = rem % SS;
    const int dyt  = rem / SS;             // 0..4
    const int tid = threadIdx.x;
    const int o    = tid >> 6;             // wave = orientation
    const int lane = tid & 63;             // e-pair index
    const int dy0 = dyt * 3;

    // stage rows [y+dy0, y+dy0+3) x 128 e (contiguous, coalesced)
    const uint4* s4 = (const uint4*)(h16 + ((size_t)b * PP + (size_t)(y + dy0) * MM) * EE);
    uint4* d4 = (uint4*)tile;
    for (int i = tid; i < 1968; i += 256) d4[i] = s4[i];
    __syncthreads();

    float acc[SS];
    #pragma unroll
    for (int x = 0; x < SS; ++x) acc[x] = 0.f;

    const uint* tl = (const uint*)tile + lane;
    const uint* wo = (const uint*)(wT16 + (((size_t)b * OO + o) * 225) * EE) + lane;

    for (int dyl = 0; dyl < 3; ++dyl) {    // NOT unrolled (spill guard)
        uint hrow[MM];
        const uint* tr = tl + (size_t)dyl * MM * 64;
        #pragma unroll
        for (int c = 0; c < MM; ++c) hrow[c] = tr[c * 64];
        const uint* wd = wo + (size_t)((dy0 + dyl) * 15) * 64;
        #pragma unroll
        for (int dx = 0; dx < 15; ++dx) {
            uint uw = wd[dx * 64];
#if __has_builtin(__builtin_amdgcn_fdot2_f32_bf16)
            bf16x2 w2 = __builtin_bit_cast(bf16x2, uw);
            #pragma unroll
            for (int x = 0; x < SS; ++x)
                acc[x] = __builtin_amdgcn_fdot2_f32_bf16(
                    __builtin_bit_cast(bf16x2, hrow[x + dx]), w2, acc[x], false);
#else
            float wl = bf2f((ushort)(uw & 0xffffu));
            float wh = bf2f((ushort)(uw >> 16));
            #pragma unroll
            for (int x = 0; x < SS; ++x) {
                uint hu = hrow[x + dx];
                acc[x] += bf2f((ushort)(hu & 0xffffu)) * wl
                        + bf2f((ushort)(hu >> 16)) * wh;
            }
#endif
        }
    }

    #pragma unroll
    for (int x = 0; x < SS; ++x) {
        float v = acc[x];
        v += __shfl_xor(v, 1);  v += __shfl_xor(v, 2);  v += __shfl_xor(v, 4);
        v += __shfl_xor(v, 8);  v += __shfl_xor(v, 16); v += __shfl_xor(v, 32);
        if (lane == 0)
            rawp[(((size_t)dyt * BB + b) * OO + o) * (SS * SS) + y * SS + x] = v;
    }
}

__global__ __launch_bounds__(256) void k_softmax(const float* __restrict__ rawp,
                                                 float* __restrict__ out,
                                                 float* __restrict__ pose, int t) {
    const int b = blockIdx.x, tid = threadIdx.x;
    const int NTOT = OO * SS * SS;
    __shared__ float sv[OO * SS * SS];
    __shared__ float red[256];

    const float* p0 = rawp + (size_t)b * NTOT;
    for (int i = tid; i < NTOT; i += 256) {
        float s = 0.f;
        #pragma unroll
        for (int q = 0; q < NPS; ++q) s += p0[(size_t)q * BB * NTOT + i];
        sv[i] = s;
    }
    __syncthreads();

    float mx = -3.4e38f;
    for (int i = tid; i < NTOT; i += 256) mx = fmaxf(mx, sv[i]);
    red[tid] = mx; __syncthreads();
    for (int s = 128; s > 0; s >>= 1) {
        if (tid < s) red[tid] = fmaxf(red[tid], red[tid + s]);
        __syncthreads();
    }
    mx = red[0]; __syncthreads();

    float sm = 0.f;
    for (int i = tid; i < NTOT; i += 256) sm += expf(sv[i] - mx);
    red[tid] = sm; __syncthreads();
    for (int s = 128; s > 0; s >>= 1) {
        if (tid < s) red[tid] += red[tid + s];
        __syncthreads();
    }
    const float inv = 1.f / red[0];

    float* rawOut = out + RAWS_OFF + ((size_t)(b * NSTEP + t) * OO) * PP;
    float* spOut  = out + SPS_OFF  + ((size_t)(b * NSTEP + t) * OO) * PP;
    float* pb = pose + (size_t)b * OO * MM * MM;
    for (int i = tid; i < OO * MM * MM; i += 256) {
        int o = i / (MM * MM), rem = i % (MM * MM), yy = rem / MM - VR, xx = rem % MM - VR;
        float rv = 0.f, sv2 = 0.f;
        if ((unsigned)yy < SS && (unsigned)xx < SS) {
            float r = sv[(o * SS + yy) * SS + xx];
            rv = r;
            sv2 = expf(r - mx) * inv;
        }
        rawOut[i] = rv;
        spOut[i] = sv2;
        pb[i] = sv2;
    }
}

extern "C" void kernel_launch(void* const* d_in, const int* in_sizes, int n_in,
                              void* d_out, int out_size, void* d_ws, size_t ws_size,
                              hipStream_t stream) {
    const float* images = (const float*)d_in[0];
    const float* wih    = (const float*)d_in[1];
    const float* whh    = (const float*)d_in[2];
    const float* bih    = (const float*)d_in[3];
    const float* bhh    = (const float*)d_in[4];
    float* out = (float*)d_out;
    float* ws  = (float*)d_ws;

    // layout (float units), total ~11.42M floats = 45.7 MB
    float*  pose  = ws;                                   // 107,584
    float*  cst   = pose + 107584;                        // 3,442,688 fp32
    ushort* hbA   = (ushort*)(cst + 3442688);             // 1,721,344 float-slots
    ushort* hbB   = (ushort*)(cst + 3442688 + 1721344);   // 1,721,344 float-slots
    float*  regbF = cst + 3442688 + 2 * 1721344;          // 3,442,688 region
    ushort* reg16 = (ushort*)regbF;                       // bf16 reg
    float*  rawp  = regbF;                                // alias (post-lstm), 233,280 fl (NPS=5)
    ushort* wT16  = (ushort*)(regbF + 3442688);           // 921,600 float-slots (own region)
    ushort* Wt    = (ushort*)(regbF + 3442688 + 921600);  // 65,536 float-slots
    float*  bc    = regbF + 3442688 + 921600 + 65536;     // 512

    hipMemsetAsync(hbA, 0, (size_t)1721344 * 4, stream);
    hipMemsetAsync(cst, 0, (size_t)3442688 * 4, stream);
    k_init<<<421, 256, 0, stream>>>(pose);
    k_prep<<<512, 256, 0, stream>>>(wih, whh, bih, bhh, Wt, bc);

    ushort* hbin = hbA;
    ushort* hbout = hbB;
    for (int t = 0; t < NSTEP; ++t) {
        k_regwprep<<<560, 256, 0, stream>>>(images, pose, reg16, wT16, t);
        k_lstm<<<dim3(211, 4), 256, 0, stream>>>(reg16, hbin, Wt, bc, hbout, cst, out, t);
        k_localize<<<2160, 256, 0, stream>>>(hbout, wT16, rawp);
        k_softmax<<<BB, 256, 0, stream>>>(rawp, out, pose, t);
        ushort* tmp = hbin; hbin = hbout; hbout = tmp;
    }
}